// Round 4
// baseline (646.187 us; speedup 1.0000x reference)
//
#include <hip/hip_runtime.h>
#include <math.h>

#define BB 4
#define TT 4096
#define DD 1024
#define FF 4096
#define NHH 16
#define HDD 64
#define KSEL 512
#define BT (BB*TT)        // 16384
#define MTOK (BB*KSEL)    // 2048
#define APAD 72

typedef __bf16 bf16x8 __attribute__((ext_vector_type(8)));
typedef __bf16 bf16x4 __attribute__((ext_vector_type(4)));
typedef float  f32x4  __attribute__((ext_vector_type(4)));

__device__ __forceinline__ void gl2lds16(const void* g, void* l) {
    __builtin_amdgcn_global_load_lds(
        (const __attribute__((address_space(1))) void*)g,
        (__attribute__((address_space(3))) void*)l,
        16, 0, 0);
}

__device__ __forceinline__ float gelu_tanh(float x) {
    return 0.5f * x * (1.0f + tanhf(0.7978845608028654f * (x + 0.044715f * x * x * x)));
}
__device__ __forceinline__ float bce_term(float x, float t) {
    return fmaxf(x, 0.f) - x * t + log1pf(expf(-fabsf(x)));
}

// ---------------- fused: passthrough copy + bf16 cast + router scores ----------------
__global__ __launch_bounds__(256) void fused_pass(const float* __restrict__ hs,
                                                  const float* __restrict__ rw,
                                                  float* __restrict__ outp,
                                                  __bf16* __restrict__ hbf,
                                                  float* __restrict__ scores) {
    int wave = threadIdx.x >> 6, lane = threadIdx.x & 63;
    int row = blockIdx.x * 4 + wave;
    long base = (long)row * DD;
    float s = 0.f;
#pragma unroll
    for (int it = 0; it < 4; ++it) {
        int c = it * 256 + lane * 4;
        float4 v = *(const float4*)(hs + base + c);
        *(float4*)(outp + base + c) = v;
        float4 r4 = *(const float4*)(rw + c);
        s += v.x * r4.x + v.y * r4.y + v.z * r4.z + v.w * r4.w;
        bf16x4 b4 = {(__bf16)v.x, (__bf16)v.y, (__bf16)v.z, (__bf16)v.w};
        *(bf16x4*)(hbf + base + c) = b4;
    }
    for (int off = 32; off > 0; off >>= 1) s += __shfl_down(s, off, 64);
    if (lane == 0) scores[row] = s;
}

// ---------------- top-k per batch: bitonic sort ----------------
__global__ __launch_bounds__(1024) void topk_kernel(const float* __restrict__ scores,
                                                    float* __restrict__ flags,
                                                    int* __restrict__ idx_out,
                                                    float* __restrict__ gate_out) {
    int b = blockIdx.x;
    int tid = threadIdx.x;
    __shared__ float sv[TT];
    __shared__ int   si[TT];
    __shared__ int   tmp[KSEL];
    const float* sc = scores + b * TT;
    for (int i = tid; i < TT; i += 1024) { sv[i] = sc[i]; si[i] = i; }
    __syncthreads();
    for (int k2 = 2; k2 <= TT; k2 <<= 1) {
        for (int j = k2 >> 1; j > 0; j >>= 1) {
            for (int i = tid; i < TT; i += 1024) {
                int ixj = i ^ j;
                if (ixj > i) {
                    float s1 = sv[i], s2 = sv[ixj];
                    int i1 = si[i], i2 = si[ixj];
                    bool before = (s1 > s2) || (s1 == s2 && i1 < i2);
                    bool up = (i & k2) == 0;
                    if (up ? !before : before) {
                        sv[i] = s2; sv[ixj] = s1; si[i] = i2; si[ixj] = i1;
                    }
                }
            }
            __syncthreads();
        }
    }
    for (int i = tid; i < TT; i += 1024) flags[b * TT + i] = 0.f;
    __syncthreads();
    if (tid < KSEL) { tmp[tid] = si[tid]; flags[b * TT + si[tid]] = 1.0f; }
    __syncthreads();
    for (int k2 = 2; k2 <= KSEL; k2 <<= 1) {
        for (int j = k2 >> 1; j > 0; j >>= 1) {
            if (tid < KSEL) {
                int i = tid, ixj = tid ^ j;
                if (ixj > i) {
                    int a = tmp[i], c = tmp[ixj];
                    bool up = (i & k2) == 0;
                    if (up ? (a > c) : (a < c)) { tmp[i] = c; tmp[ixj] = a; }
                }
            }
            __syncthreads();
        }
    }
    if (tid < KSEL) {
        int t2 = tmp[tid];
        idx_out[b * KSEL + tid] = t2;
        float s = sc[t2];
        gate_out[b * KSEL + tid] = 1.0f / (1.0f + expf(-s));
    }
}

// ---------------- multi-weight cast+transpose: f32 [K][N] -> bf16 [N][K] ----------------
// ilv: 0 none; 1 gate-interleave (row = ((n>>4)<<5)+(n&15)); 2 up (+16)
struct CDesc { const float* src; __bf16* dst; int K, N, start, ilv; };
struct CPack { CDesc d[5]; int nd; };

__global__ __launch_bounds__(256) void cast_multi(CPack p) {
    int bid = blockIdx.x, di = 0;
    while (di + 1 < p.nd && bid >= p.d[di + 1].start) ++di;
    const float* src = p.d[di].src;
    __bf16* dst = p.d[di].dst;
    int K = p.d[di].K, N = p.d[di].N, ilv = p.d[di].ilv;
    int local = bid - p.d[di].start;
    int tn = N >> 5;
    int n0 = (local % tn) * 32, k0 = (local / tn) * 32;
    __shared__ float tile[32][33];
    int tx = threadIdx.x & 31, ty = threadIdx.x >> 5;
#pragma unroll
    for (int i = 0; i < 32; i += 8)
        tile[ty + i][tx] = src[(long)(k0 + ty + i) * N + n0 + tx];
    __syncthreads();
#pragma unroll
    for (int i = 0; i < 32; i += 8) {
        int n = n0 + ty + i;
        int orow = n;
        if (ilv) orow = ((n >> 4) << 5) + (n & 15) + ((ilv == 2) ? 16 : 0);
        dst[(long)orow * K + k0 + tx] = (__bf16)tile[tx][ty + i];
    }
}

// ---------------- MFMA GEMM: A[MxK] bf16, Bt[NxK] bf16, 128x128 tile ----------------
// EP 1: Cbf = gather(hid,idx) + A@B            [wo + residual]
// EP 3: logits[row] += sum_n gelu(A@B+bias)*w2 [predictor]
// EP 4: swiglu on interleaved gate/up pairs -> act quarters
// EP 6: qkv with fused rope on q,k
template <int EP>
__global__ __launch_bounds__(256) void mfma_gemm(const __bf16* __restrict__ Abf,
                                                 const __bf16* __restrict__ Bt,
                                                 int M, int N, int K,
                                                 __bf16* __restrict__ Cbf,
                                                 const float* __restrict__ hid,
                                                 const int* __restrict__ idxp,
                                                 const float* __restrict__ bias,
                                                 const float* __restrict__ w2,
                                                 float* __restrict__ logits,
                                                 __bf16* __restrict__ q0,
                                                 __bf16* __restrict__ q1,
                                                 __bf16* __restrict__ q2,
                                                 __bf16* __restrict__ q3) {
    __shared__ __bf16 As[128 * 32];
    __shared__ __bf16 Bs[128 * 32];
    int tid = threadIdx.x;
    int lane = tid & 63, wave = tid >> 6;
    int wm = wave >> 1, wn = wave & 1;
    int m0 = blockIdx.y * 128, n0 = blockIdx.x * 128;

    f32x4 zv = {0.f, 0.f, 0.f, 0.f};
    f32x4 acc[4][4];
#pragma unroll
    for (int i = 0; i < 4; ++i)
#pragma unroll
        for (int j = 0; j < 4; ++j) acc[i][j] = zv;

    int srow = tid >> 2;
    int scol = (tid & 3) * 8;
    long aoff = (long)(m0 + srow) * K + scol;
    long boff = (long)(n0 + srow) * K + scol;
    __bf16* ldsA = As + wave * 512;
    __bf16* ldsB = Bs + wave * 512;

    for (int k0 = 0; k0 < K; k0 += 32) {
        __syncthreads();
        gl2lds16(Abf + aoff + k0, ldsA);
        gl2lds16(Abf + aoff + (long)64 * K + k0, ldsA + 2048);
        gl2lds16(Bt + boff + k0, ldsB);
        gl2lds16(Bt + boff + (long)64 * K + k0, ldsB + 2048);
        __syncthreads();

        bf16x8 af[4], bfr[4];
#pragma unroll
        for (int mi = 0; mi < 4; ++mi)
            af[mi] = *(const bf16x8*)(As + (wm * 64 + mi * 16 + (lane & 15)) * 32 + (lane >> 4) * 8);
#pragma unroll
        for (int ni = 0; ni < 4; ++ni)
            bfr[ni] = *(const bf16x8*)(Bs + (wn * 64 + ni * 16 + (lane & 15)) * 32 + (lane >> 4) * 8);
#pragma unroll
        for (int mi = 0; mi < 4; ++mi)
#pragma unroll
            for (int ni = 0; ni < 4; ++ni)
                acc[mi][ni] = __builtin_amdgcn_mfma_f32_16x16x32_bf16(af[mi], bfr[ni], acc[mi][ni], 0, 0, 0);
    }

    int cm = (lane >> 4) * 4;
    int cn = lane & 15;
    if (EP == 3) {
#pragma unroll
        for (int mi = 0; mi < 4; ++mi) {
#pragma unroll
            for (int r = 0; r < 4; ++r) {
                float part = 0.f;
#pragma unroll
                for (int ni = 0; ni < 4; ++ni) {
                    int gn = n0 + wn * 64 + ni * 16 + cn;
                    float x = acc[mi][ni][r] + bias[gn];
                    part += gelu_tanh(x) * w2[gn];
                }
                part += __shfl_xor(part, 1, 64);
                part += __shfl_xor(part, 2, 64);
                part += __shfl_xor(part, 4, 64);
                part += __shfl_xor(part, 8, 64);
                if ((lane & 15) == 0)
                    atomicAdd(&logits[m0 + wm * 64 + mi * 16 + cm + r], part);
            }
        }
    } else if (EP == 4) {
        __bf16* qs[4] = {q0, q1, q2, q3};
        int colbase = (n0 >> 1) + wn * 32;
        __bf16* qp = qs[colbase >> 10];
        int cb = colbase & 1023;
#pragma unroll
        for (int mi = 0; mi < 4; ++mi)
#pragma unroll
            for (int pi = 0; pi < 2; ++pi)
#pragma unroll
                for (int r = 0; r < 4; ++r) {
                    int gm = m0 + wm * 64 + mi * 16 + cm + r;
                    float g = acc[mi][2 * pi][r];
                    float u = acc[mi][2 * pi + 1][r];
                    float sl = g / (1.0f + expf(-g));
                    qp[(long)gm * 1024 + cb + pi * 16 + cn] = (__bf16)(sl * u);
                }
    } else if (EP == 6) {
        int g64 = n0 + wn * 64;
        if (g64 < 2048) {
            float inv0 = exp2f(-(float)cn * 0.41524101186f);
            float inv1 = exp2f(-(float)(cn + 16) * 0.41524101186f);
#pragma unroll
            for (int mi = 0; mi < 4; ++mi)
#pragma unroll
                for (int r = 0; r < 4; ++r) {
                    int gm = m0 + wm * 64 + mi * 16 + cm + r;
                    float pos = (float)idxp[gm];
                    float a0 = pos * inv0, a1 = pos * inv1;
                    float c0 = cosf(a0), s0 = sinf(a0);
                    float c1 = cosf(a1), s1 = sinf(a1);
                    float x1 = acc[mi][0][r], x2 = acc[mi][2][r];
                    float y1 = acc[mi][1][r], y2 = acc[mi][3][r];
                    long ob = (long)gm * N + g64;
                    Cbf[ob + cn]      = (__bf16)(x1 * c0 - x2 * s0);
                    Cbf[ob + cn + 32] = (__bf16)(x2 * c0 + x1 * s0);
                    Cbf[ob + cn + 16] = (__bf16)(y1 * c1 - y2 * s1);
                    Cbf[ob + cn + 48] = (__bf16)(y2 * c1 + y1 * s1);
                }
        } else {
#pragma unroll
            for (int mi = 0; mi < 4; ++mi)
#pragma unroll
                for (int ni = 0; ni < 4; ++ni)
#pragma unroll
                    for (int r = 0; r < 4; ++r) {
                        int gm = m0 + wm * 64 + mi * 16 + cm + r;
                        Cbf[(long)gm * N + g64 + ni * 16 + cn] = (__bf16)acc[mi][ni][r];
                    }
        }
    } else {  // EP == 1
#pragma unroll
        for (int mi = 0; mi < 4; ++mi)
#pragma unroll
            for (int ni = 0; ni < 4; ++ni)
#pragma unroll
                for (int r = 0; r < 4; ++r) {
                    int gm = m0 + wm * 64 + mi * 16 + cm + r;
                    int gn = n0 + wn * 64 + ni * 16 + cn;
                    int b = gm >> 9;
                    int row = idxp[gm];
                    float selv = hid[((long)b * TT + row) * DD + gn];
                    Cbf[(long)gm * N + gn] = (__bf16)(selv + acc[mi][ni][r]);
                }
    }
}

// ---------------- down proj: split-K=2, A from act quarters, bf16 partials ----------------
__global__ __launch_bounds__(256) void down_gemm(const __bf16* __restrict__ a0,
                                                 const __bf16* __restrict__ a1,
                                                 const __bf16* __restrict__ a2,
                                                 const __bf16* __restrict__ a3,
                                                 const __bf16* __restrict__ Bt,
                                                 __bf16* __restrict__ p0,
                                                 __bf16* __restrict__ p1) {
    __shared__ __bf16 As[128 * 32];
    __shared__ __bf16 Bs[128 * 32];
    int tid = threadIdx.x;
    int lane = tid & 63, wave = tid >> 6;
    int wm = wave >> 1, wn = wave & 1;
    int m0 = blockIdx.y * 128, n0 = blockIdx.x * 128;
    int z = blockIdx.z;
    const __bf16* qs[4] = {a0, a1, a2, a3};

    f32x4 zv = {0.f, 0.f, 0.f, 0.f};
    f32x4 acc[4][4];
#pragma unroll
    for (int i = 0; i < 4; ++i)
#pragma unroll
        for (int j = 0; j < 4; ++j) acc[i][j] = zv;

    int srow = tid >> 2;
    int scol = (tid & 3) * 8;
    long boff = (long)(n0 + srow) * 4096 + z * 2048 + scol;
    __bf16* ldsA = As + wave * 512;
    __bf16* ldsB = Bs + wave * 512;

    for (int k0 = 0; k0 < 2048; k0 += 32) {
        const __bf16* ap = qs[z * 2 + (k0 >> 10)];
        long aoff = (long)(m0 + srow) * 1024 + (k0 & 1023) + scol;
        __syncthreads();
        gl2lds16(ap + aoff, ldsA);
        gl2lds16(ap + aoff + (long)64 * 1024, ldsA + 2048);
        gl2lds16(Bt + boff + k0, ldsB);
        gl2lds16(Bt + boff + (long)64 * 4096 + k0, ldsB + 2048);
        __syncthreads();

        bf16x8 af[4], bfr[4];
#pragma unroll
        for (int mi = 0; mi < 4; ++mi)
            af[mi] = *(const bf16x8*)(As + (wm * 64 + mi * 16 + (lane & 15)) * 32 + (lane >> 4) * 8);
#pragma unroll
        for (int ni = 0; ni < 4; ++ni)
            bfr[ni] = *(const bf16x8*)(Bs + (wn * 64 + ni * 16 + (lane & 15)) * 32 + (lane >> 4) * 8);
#pragma unroll
        for (int mi = 0; mi < 4; ++mi)
#pragma unroll
            for (int ni = 0; ni < 4; ++ni)
                acc[mi][ni] = __builtin_amdgcn_mfma_f32_16x16x32_bf16(af[mi], bfr[ni], acc[mi][ni], 0, 0, 0);
    }

    int cm = (lane >> 4) * 4;
    int cn = lane & 15;
    __bf16* pz = z ? p1 : p0;
#pragma unroll
    for (int mi = 0; mi < 4; ++mi)
#pragma unroll
        for (int ni = 0; ni < 4; ++ni)
#pragma unroll
            for (int r = 0; r < 4; ++r) {
                int gm = m0 + wm * 64 + mi * 16 + cm + r;
                int gn = n0 + wn * 64 + ni * 16 + cn;
                pz[(long)gm * 1024 + gn] = (__bf16)acc[mi][ni][r];
            }
}

// ---------------- combine partials + gated scatter ----------------
__global__ __launch_bounds__(256) void scatter_kernel(const __bf16* __restrict__ p0,
                                                      const __bf16* __restrict__ p1,
                                                      const __bf16* __restrict__ hbf,
                                                      const float* __restrict__ hid,
                                                      const int* __restrict__ idxp,
                                                      const float* __restrict__ gatep,
                                                      float* __restrict__ outp) {
    int m = blockIdx.x;
    int c = threadIdx.x * 4;
    int b = m >> 9;
    int row = idxp[m];
    float gv = gatep[m];
    long pb = (long)m * DD + c;
    bf16x4 v0 = *(const bf16x4*)(p0 + pb);
    bf16x4 v1 = *(const bf16x4*)(p1 + pb);
    bf16x4 hh = *(const bf16x4*)(hbf + pb);
    long ob = ((long)b * TT + row) * DD + c;
    float4 sel = *(const float4*)(hid + ob);
    float4 o;
    o.x = sel.x + gv * ((float)hh[0] + (float)v0[0] + (float)v1[0] - sel.x);
    o.y = sel.y + gv * ((float)hh[1] + (float)v0[1] + (float)v1[1] - sel.y);
    o.z = sel.z + gv * ((float)hh[2] + (float)v0[2] + (float)v1[2] - sel.z);
    o.w = sel.w + gv * ((float)hh[3] + (float)v0[3] + (float)v1[3] - sel.w);
    *(float4*)(outp + ob) = o;
}

// ---------------- rmsnorm: f32-gather or bf16 input, bf16 out ----------------
template <typename TIN>
__global__ __launch_bounds__(256) void rms_kernel(const TIN* __restrict__ src,
                                                  const int* __restrict__ idx,
                                                  const float* __restrict__ gamma,
                                                  __bf16* __restrict__ out) {
    int m = blockIdx.x;
    int tid = threadIdx.x;
    long srow;
    if (idx) {
        int b = m >> 9;
        srow = ((long)b * TT + idx[m]) * DD;
    } else {
        srow = (long)m * DD;
    }
    __shared__ float red[256];
    float v[4];
#pragma unroll
    for (int i = 0; i < 4; ++i) v[i] = (float)src[srow + tid * 4 + i];
    float ss = v[0] * v[0] + v[1] * v[1] + v[2] * v[2] + v[3] * v[3];
    red[tid] = ss;
    __syncthreads();
    for (int s2 = 128; s2 > 0; s2 >>= 1) {
        if (tid < s2) red[tid] += red[tid + s2];
        __syncthreads();
    }
    float r = rsqrtf(red[0] / (float)DD + 1e-6f);
    float4 g4 = *(const float4*)(gamma + tid * 4);
    long obase = (long)m * DD + tid * 4;
    out[obase + 0] = (__bf16)(v[0] * r * g4.x);
    out[obase + 1] = (__bf16)(v[1] * r * g4.y);
    out[obase + 2] = (__bf16)(v[2] * r * g4.z);
    out[obase + 3] = (__bf16)(v[3] * r * g4.w);
}

// ---------------- MFMA flash attention ----------------
__global__ __launch_bounds__(256) void attn_mfma(const __bf16* __restrict__ qkv,
                                                 __bf16* __restrict__ o) {
    int qt = blockIdx.x;
    int bh = blockIdx.y;
    int b = bh >> 4, h = bh & 15;
    int tid = threadIdx.x;
    int lane = tid & 63, w = tid >> 6;
    __shared__ __bf16 Ks[64 * APAD];
    __shared__ __bf16 Vt[64 * APAD];
    __shared__ __bf16 Ps[4][16 * APAD];

    int l15 = lane & 15, l4 = lane >> 4;
    int qrow0 = b * KSEL + qt * 64 + w * 16;
    bf16x8 qf[2];
    {
        long base = ((long)(qrow0 + l15)) * 3072 + h * 64 + l4 * 8;
        qf[0] = *(const bf16x8*)(qkv + base);
        qf[1] = *(const bf16x8*)(qkv + base + 32);
    }
    float m_run[4], l_run[4];
    f32x4 O[4];
#pragma unroll
    for (int r = 0; r < 4; ++r) { m_run[r] = -1e30f; l_run[r] = 0.f; }
    f32x4 zv = {0.f, 0.f, 0.f, 0.f};
#pragma unroll
    for (int ni = 0; ni < 4; ++ni) O[ni] = zv;

    int sr = tid & 63;
    int sg = tid >> 6;
    for (int kt = 0; kt <= qt; ++kt) {
        __syncthreads();
        long kvbase = ((long)(b * KSEL + kt * 64 + sr)) * 3072 + h * 64 + 1024;
        bf16x8 kv0 = *(const bf16x8*)(qkv + kvbase + sg * 16);
        bf16x8 kv1 = *(const bf16x8*)(qkv + kvbase + sg * 16 + 8);
        *(bf16x8*)(Ks + sr * APAD + sg * 16) = kv0;
        *(bf16x8*)(Ks + sr * APAD + sg * 16 + 8) = kv1;
        bf16x8 vv0 = *(const bf16x8*)(qkv + kvbase + 1024 + sg * 16);
        bf16x8 vv1 = *(const bf16x8*)(qkv + kvbase + 1024 + sg * 16 + 8);
#pragma unroll
        for (int i = 0; i < 8; ++i) {
            Vt[(sg * 16 + i) * APAD + sr] = vv0[i];
            Vt[(sg * 16 + 8 + i) * APAD + sr] = vv1[i];
        }
        __syncthreads();

        f32x4 S[4];
#pragma unroll
        for (int ni = 0; ni < 4; ++ni) S[ni] = zv;
#pragma unroll
        for (int ni = 0; ni < 4; ++ni) {
            bf16x8 kf0 = *(const bf16x8*)(Ks + (ni * 16 + l15) * APAD + l4 * 8);
            bf16x8 kf1 = *(const bf16x8*)(Ks + (ni * 16 + l15) * APAD + l4 * 8 + 32);
            S[ni] = __builtin_amdgcn_mfma_f32_16x16x32_bf16(qf[0], kf0, S[ni], 0, 0, 0);
            S[ni] = __builtin_amdgcn_mfma_f32_16x16x32_bf16(qf[1], kf1, S[ni], 0, 0, 0);
        }
        int rowb = qt * 64 + w * 16 + l4 * 4;
#pragma unroll
        for (int r = 0; r < 4; ++r) {
            float sv[4];
            float mx = -1e30f;
#pragma unroll
            for (int ni = 0; ni < 4; ++ni) {
                float x = S[ni][r] * 0.125f;
                int col = kt * 64 + ni * 16 + l15;
                if (col > rowb + r) x = -1e30f;
                sv[ni] = x;
                mx = fmaxf(mx, x);
            }
            mx = fmaxf(mx, __shfl_xor(mx, 1, 64));
            mx = fmaxf(mx, __shfl_xor(mx, 2, 64));
            mx = fmaxf(mx, __shfl_xor(mx, 4, 64));
            mx = fmaxf(mx, __shfl_xor(mx, 8, 64));
            float m_new = fmaxf(m_run[r], mx);
            float alpha = expf(m_run[r] - m_new);
            float ps = 0.f;
#pragma unroll
            for (int ni = 0; ni < 4; ++ni) {
                float e = expf(sv[ni] - m_new);
                sv[ni] = e;
                ps += e;
            }
            ps += __shfl_xor(ps, 1, 64);
            ps += __shfl_xor(ps, 2, 64);
            ps += __shfl_xor(ps, 4, 64);
            ps += __shfl_xor(ps, 8, 64);
            l_run[r] = l_run[r] * alpha + ps;
            m_run[r] = m_new;
#pragma unroll
            for (int ni = 0; ni < 4; ++ni) {
                O[ni][r] *= alpha;
                Ps[w][(l4 * 4 + r) * APAD + ni * 16 + l15] = (__bf16)sv[ni];
            }
        }
#pragma unroll
        for (int ks = 0; ks < 2; ++ks) {
            bf16x8 pf = *(const bf16x8*)(Ps[w] + l15 * APAD + ks * 32 + l4 * 8);
#pragma unroll
            for (int ni = 0; ni < 4; ++ni) {
                bf16x8 vf = *(const bf16x8*)(Vt + (ni * 16 + l15) * APAD + ks * 32 + l4 * 8);
                O[ni] = __builtin_amdgcn_mfma_f32_16x16x32_bf16(pf, vf, O[ni], 0, 0, 0);
            }
        }
    }
    long orow = (long)(b * KSEL + qt * 64 + w * 16);
#pragma unroll
    for (int r = 0; r < 4; ++r) {
        float inv = 1.0f / l_run[r];
#pragma unroll
        for (int ni = 0; ni < 4; ++ni)
            o[(orow + l4 * 4 + r) * DD + h * 64 + ni * 16 + l15] = (__bf16)(O[ni][r] * inv);
    }
}

// ---------------- BCE losses ----------------
__global__ __launch_bounds__(256) void bce_kernel(const float* __restrict__ scores,
                                                  const float* __restrict__ logits,
                                                  const float* __restrict__ flags,
                                                  const float* __restrict__ fc2b,
                                                  float* __restrict__ acc) {
    int i = blockIdx.x * 256 + threadIdx.x;
    int tid = threadIdx.x;
    __shared__ float r0[256];
    __shared__ float r1[256];
    float tgt = flags[i];
    r0[tid] = bce_term(scores[i], tgt);
    r1[tid] = bce_term(logits[i] + fc2b[0], tgt);
    __syncthreads();
    for (int s2 = 128; s2 > 0; s2 >>= 1) {
        if (tid < s2) { r0[tid] += r0[tid + s2]; r1[tid] += r1[tid + s2]; }
        __syncthreads();
    }
    if (tid == 0) {
        atomicAdd(acc + 0, r0[0]);
        atomicAdd(acc + 1, r1[0]);
    }
}

__global__ void finalize_kernel(const float* __restrict__ acc, float* __restrict__ out) {
    out[0] = (acc[0] / (float)BT) * 0.01f + (acc[1] / (float)BT) * 0.01f;
}

extern "C" void kernel_launch(void* const* d_in, const int* in_sizes, int n_in,
                              void* d_out, int out_size, void* d_ws, size_t ws_size,
                              hipStream_t stream) {
    const float* hidden = (const float*)d_in[0];
    const float* router_w = (const float*)d_in[1];
    const float* fc1_w = (const float*)d_in[2];
    const float* fc1_b = (const float*)d_in[3];
    const float* fc2_w = (const float*)d_in[4];
    const float* fc2_b = (const float*)d_in[5];
    const float* ln1_g = (const float*)d_in[6];
    const float* ln2_g = (const float*)d_in[7];
    const float* wq = (const float*)d_in[8];
    const float* wk = (const float*)d_in[9];
    const float* wv = (const float*)d_in[10];
    const float* wo = (const float*)d_in[11];
    const float* w_gate = (const float*)d_in[12];
    const float* w_up = (const float*)d_in[13];
    const float* w_down = (const float*)d_in[14];

    float* out = (float*)d_out;
    char* wsb = (char*)d_ws;

    // ---- workspace layout (peak 48.75 MiB; ~58.9 MB proven available) ----
    float* scores = (float*)(wsb);                 // 64K
    float* flags  = (float*)(wsb + 0x10000);       // 64K
    float* logits = (float*)(wsb + 0x20000);       // 64K
    int*   idx    = (int*)  (wsb + 0x30000);       // 8K
    float* gate   = (float*)(wsb + 0x32000);       // 8K
    float* acc    = (float*)(wsb + 0x34000);
    __bf16* fc1_t  = (__bf16*)(wsb + 0x40000);     // [256][1024]  512K
    __bf16* wo_t   = (__bf16*)(wsb + 0xC0000);     // [1024][1024] 2M
    __bf16* wqkv_t = (__bf16*)(wsb + 0x2C0000);    // [3072][1024] 6M
    // ---- P region (32M, hidden_bf until predictor; overlaid after) ----
    __bf16* hidden_bf = (__bf16*)(wsb + 0x8C0000);   // 32M -> 0x28C0000
    __bf16* a_bf   = (__bf16*)(wsb + 0x8C0000);      // 4M  (rms1 -> qkvGEMM)
    __bf16* qkv    = (__bf16*)(wsb + 0xCC0000);      // 12M (qkvGEMM -> attn)
    __bf16* att_bf = (__bf16*)(wsb + 0x18C0000);     // 4M  (attn -> wo)
    __bf16* h_bf   = (__bf16*)(wsb + 0x1CC0000);     // 4M  (wo -> scatter)
    __bf16* m_bf   = (__bf16*)(wsb + 0x20C0000);     // 4M  (rms2 -> gateup)
    __bf16* wgu_t  = (__bf16*)(wsb + 0x8C0000);      // 16M (cast after attn -> gateup)
    __bf16* wd_t   = (__bf16*)(wsb + 0x8C0000);      // 8M  (cast after gateup -> down)
    __bf16* p0     = (__bf16*)(wsb + 0x10C0000);     // 4M  (down -> scatter)
    __bf16* p1     = (__bf16*)(wsb + 0x14C0000);     // 4M
    __bf16* actq0  = (__bf16*)(wsb + 0x18C0000);     // 4M  (gateup -> down; att dead)
    __bf16* actq1  = (__bf16*)(wsb + 0x24C0000);     // 4M
    __bf16* actq2  = (__bf16*)(wsb + 0x28C0000);     // 4M
    __bf16* actq3  = (__bf16*)(wsb + 0x2CC0000);     // 4M -> end 0x30C0000

    // 1. zero accumulators
    hipMemsetAsync(acc, 0, 2 * sizeof(float), stream);
    hipMemsetAsync(logits, 0, BT * sizeof(float), stream);

    // 2. early weight casts (fc1, wq, wk, wv, wo) in one kernel
    {
        CPack p;
        p.nd = 5;
        p.d[0] = {fc1_w, fc1_t, DD, 256, 0, 0};                              // 256 tiles
        p.d[1] = {wq, wqkv_t, DD, DD, 256, 0};                               // 1024
        p.d[2] = {wk, wqkv_t + (size_t)1024 * 1024, DD, DD, 1280, 0};        // 1024
        p.d[3] = {wv, wqkv_t + (size_t)2048 * 1024, DD, DD, 2304, 0};        // 1024
        p.d[4] = {wo, wo_t, DD, DD, 3328, 0};                                // 1024
        cast_multi<<<4352, 256, 0, stream>>>(p);
    }

    // 3. fused passthrough copy + bf16 cast + router scores; top-k
    fused_pass<<<BT / 4, 256, 0, stream>>>(hidden, router_w, out, hidden_bf, scores);
    topk_kernel<<<BB, 1024, 0, stream>>>(scores, flags, idx, gate);

    // 4. predictor GEMM + BCE
    mfma_gemm<3><<<dim3(2, BT / 128), 256, 0, stream>>>(
        hidden_bf, fc1_t, BT, 256, DD, nullptr, nullptr, nullptr,
        fc1_b, fc2_w, logits, nullptr, nullptr, nullptr, nullptr);
    bce_kernel<<<BT / 256, 256, 0, stream>>>(scores, logits, flags, fc2_b, acc);

    // 5. gather + rmsnorm1 -> a_bf
    rms_kernel<float><<<MTOK, 256, 0, stream>>>(hidden, idx, ln1_g, a_bf);

    // 6. fused qkv projection with in-epilogue RoPE
    mfma_gemm<6><<<dim3(3072 / 128, MTOK / 128), 256, 0, stream>>>(
        a_bf, wqkv_t, MTOK, 3072, DD, qkv, nullptr, idx,
        nullptr, nullptr, nullptr, nullptr, nullptr, nullptr, nullptr);

    // 7. MFMA flash attention
    attn_mfma<<<dim3(KSEL / 64, BB * NHH), 256, 0, stream>>>(qkv, att_bf);

    // 8. cast wg/wu interleaved -> wgu_t (a_bf, qkv now dead)
    {
        CPack p;
        p.nd = 2;
        p.d[0] = {w_gate, wgu_t, DD, FF, 0, 1};     // 4096 tiles
        p.d[1] = {w_up,   wgu_t, DD, FF, 4096, 2};  // 4096
        cast_multi<<<8192, 256, 0, stream>>>(p);
    }

    // 9. Wo + residual -> h_bf
    mfma_gemm<1><<<dim3(DD / 128, MTOK / 128), 256, 0, stream>>>(
        att_bf, wo_t, MTOK, DD, DD, h_bf, hidden, idx,
        nullptr, nullptr, nullptr, nullptr, nullptr, nullptr, nullptr);

    // 10. rmsnorm2 -> m_bf
    rms_kernel<__bf16><<<MTOK, 256, 0, stream>>>(h_bf, nullptr, ln2_g, m_bf);

    // 11. fused SwiGLU gate/up (interleaved N=8192) -> act quarters
    mfma_gemm<4><<<dim3(8192 / 128, MTOK / 128), 256, 0, stream>>>(
        m_bf, wgu_t, MTOK, 8192, DD, nullptr, nullptr, nullptr,
        nullptr, nullptr, nullptr, actq0, actq1, actq2, actq3);

    // 12. cast w_down -> wd_t (wgu dead)
    {
        CPack p;
        p.nd = 1;
        p.d[0] = {w_down, wd_t, FF, DD, 0, 0};      // 4096 tiles
        cast_multi<<<4096, 256, 0, stream>>>(p);
    }

    // 13. down proj split-K=2 -> bf16 partials
    down_gemm<<<dim3(DD / 128, MTOK / 128, 2), 256, 0, stream>>>(
        actq0, actq1, actq2, actq3, wd_t, p0, p1);

    // 14. combine partials + gated scatter into out
    scatter_kernel<<<MTOK, 256, 0, stream>>>(p0, p1, h_bf, hidden, idx, gate, out);

    // 15. aux scalar
    finalize_kernel<<<1, 1, 0, stream>>>(acc, out + (size_t)BT * DD);
}

// Round 5
// 524.515 us; speedup vs baseline: 1.2320x; 1.2320x over previous
//
#include <hip/hip_runtime.h>
#include <math.h>

#define BB 4
#define TT 4096
#define DD 1024
#define FF 4096
#define NHH 16
#define HDD 64
#define KSEL 512
#define BT (BB*TT)        // 16384
#define MTOK (BB*KSEL)    // 2048
#define APAD 72

typedef __bf16 bf16x8 __attribute__((ext_vector_type(8)));
typedef __bf16 bf16x4 __attribute__((ext_vector_type(4)));
typedef float  f32x4  __attribute__((ext_vector_type(4)));

__device__ __forceinline__ void gl2lds16(const void* g, void* l) {
    __builtin_amdgcn_global_load_lds(
        (const __attribute__((address_space(1))) void*)g,
        (__attribute__((address_space(3))) void*)l,
        16, 0, 0);
}

__device__ __forceinline__ float gelu_tanh(float x) {
    return 0.5f * x * (1.0f + tanhf(0.7978845608028654f * (x + 0.044715f * x * x * x)));
}
__device__ __forceinline__ float bce_term(float x, float t) {
    return fmaxf(x, 0.f) - x * t + log1pf(expf(-fabsf(x)));
}

// ---------------- fused: passthrough copy + bf16 cast + router scores ----------------
__global__ __launch_bounds__(256) void fused_pass(const float* __restrict__ hs,
                                                  const float* __restrict__ rw,
                                                  float* __restrict__ outp,
                                                  __bf16* __restrict__ hbf,
                                                  float* __restrict__ scores) {
    int wave = threadIdx.x >> 6, lane = threadIdx.x & 63;
    int row = blockIdx.x * 4 + wave;
    long base = (long)row * DD;
    float s = 0.f;
#pragma unroll
    for (int it = 0; it < 4; ++it) {
        int c = it * 256 + lane * 4;
        float4 v = *(const float4*)(hs + base + c);
        *(float4*)(outp + base + c) = v;
        float4 r4 = *(const float4*)(rw + c);
        s += v.x * r4.x + v.y * r4.y + v.z * r4.z + v.w * r4.w;
        bf16x4 b4 = {(__bf16)v.x, (__bf16)v.y, (__bf16)v.z, (__bf16)v.w};
        *(bf16x4*)(hbf + base + c) = b4;
    }
    for (int off = 32; off > 0; off >>= 1) s += __shfl_down(s, off, 64);
    if (lane == 0) scores[row] = s;
}

// ---------------- top-k per batch: bitonic sort ----------------
__global__ __launch_bounds__(1024) void topk_kernel(const float* __restrict__ scores,
                                                    float* __restrict__ flags,
                                                    int* __restrict__ idx_out,
                                                    float* __restrict__ gate_out) {
    int b = blockIdx.x;
    int tid = threadIdx.x;
    __shared__ float sv[TT];
    __shared__ int   si[TT];
    __shared__ int   tmp[KSEL];
    const float* sc = scores + b * TT;
    for (int i = tid; i < TT; i += 1024) { sv[i] = sc[i]; si[i] = i; }
    __syncthreads();
    for (int k2 = 2; k2 <= TT; k2 <<= 1) {
        for (int j = k2 >> 1; j > 0; j >>= 1) {
            for (int i = tid; i < TT; i += 1024) {
                int ixj = i ^ j;
                if (ixj > i) {
                    float s1 = sv[i], s2 = sv[ixj];
                    int i1 = si[i], i2 = si[ixj];
                    bool before = (s1 > s2) || (s1 == s2 && i1 < i2);
                    bool up = (i & k2) == 0;
                    if (up ? !before : before) {
                        sv[i] = s2; sv[ixj] = s1; si[i] = i2; si[ixj] = i1;
                    }
                }
            }
            __syncthreads();
        }
    }
    for (int i = tid; i < TT; i += 1024) flags[b * TT + i] = 0.f;
    __syncthreads();
    if (tid < KSEL) { tmp[tid] = si[tid]; flags[b * TT + si[tid]] = 1.0f; }
    __syncthreads();
    for (int k2 = 2; k2 <= KSEL; k2 <<= 1) {
        for (int j = k2 >> 1; j > 0; j >>= 1) {
            if (tid < KSEL) {
                int i = tid, ixj = tid ^ j;
                if (ixj > i) {
                    int a = tmp[i], c = tmp[ixj];
                    bool up = (i & k2) == 0;
                    if (up ? (a > c) : (a < c)) { tmp[i] = c; tmp[ixj] = a; }
                }
            }
            __syncthreads();
        }
    }
    if (tid < KSEL) {
        int t2 = tmp[tid];
        idx_out[b * KSEL + tid] = t2;
        float s = sc[t2];
        gate_out[b * KSEL + tid] = 1.0f / (1.0f + expf(-s));
    }
}

// ---------------- multi-weight cast+transpose: f32 [K][N] -> bf16 [N][K] ----------------
// ilv: 0 none; 1 gate-interleave (row = (n>>4)*32 + (n&15)); 2 up (+16)
struct CDesc { const float* src; __bf16* dst; int K, N, start, ilv; };
struct CPack { CDesc d[5]; int nd; };

__global__ __launch_bounds__(256) void cast_multi(CPack p) {
    int bid = blockIdx.x, di = 0;
    while (di + 1 < p.nd && bid >= p.d[di + 1].start) ++di;
    const float* src = p.d[di].src;
    __bf16* dst = p.d[di].dst;
    int K = p.d[di].K, N = p.d[di].N, ilv = p.d[di].ilv;
    int local = bid - p.d[di].start;
    int tn = N >> 5;
    int n0 = (local % tn) * 32, k0 = (local / tn) * 32;
    __shared__ float tile[32][33];
    int tx = threadIdx.x & 31, ty = threadIdx.x >> 5;
#pragma unroll
    for (int i = 0; i < 32; i += 8)
        tile[ty + i][tx] = src[(long)(k0 + ty + i) * N + n0 + tx];
    __syncthreads();
#pragma unroll
    for (int i = 0; i < 32; i += 8) {
        int n = n0 + ty + i;
        int orow = n;
        if (ilv) orow = ((n >> 4) << 5) + (n & 15) + ((ilv == 2) ? 16 : 0);
        dst[(long)orow * K + k0 + tx] = (__bf16)tile[tx][ty + i];
    }
}

// ---------------- MFMA GEMM: A[MxK] bf16, Bt[NxK] bf16, 128x128 tile ----------------
// EP 0: Cbf = A@B
// EP 1: Cbf = gather(hid,idx) + A@B            [wo + residual]
// EP 3: logits[row] += sum_n gelu(A@B+bias)*w2 [predictor]
template <int EP>
__global__ __launch_bounds__(256) void mfma_gemm(const __bf16* __restrict__ Abf,
                                                 const __bf16* __restrict__ Bt,
                                                 int M, int N, int K,
                                                 __bf16* __restrict__ Cbf,
                                                 const float* __restrict__ hid,
                                                 const int* __restrict__ idxp,
                                                 const float* __restrict__ bias,
                                                 const float* __restrict__ w2,
                                                 float* __restrict__ logits) {
    __shared__ __bf16 As[128 * 32];
    __shared__ __bf16 Bs[128 * 32];
    int tid = threadIdx.x;
    int lane = tid & 63, wave = tid >> 6;
    int wm = wave >> 1, wn = wave & 1;
    int m0 = blockIdx.y * 128, n0 = blockIdx.x * 128;

    f32x4 zv = {0.f, 0.f, 0.f, 0.f};
    f32x4 acc[4][4];
#pragma unroll
    for (int i = 0; i < 4; ++i)
#pragma unroll
        for (int j = 0; j < 4; ++j) acc[i][j] = zv;

    int srow = tid >> 2;
    int scol = (tid & 3) * 8;
    long aoff = (long)(m0 + srow) * K + scol;
    long boff = (long)(n0 + srow) * K + scol;
    __bf16* ldsA = As + wave * 512;
    __bf16* ldsB = Bs + wave * 512;

    for (int k0 = 0; k0 < K; k0 += 32) {
        __syncthreads();
        gl2lds16(Abf + aoff + k0, ldsA);
        gl2lds16(Abf + aoff + (long)64 * K + k0, ldsA + 2048);
        gl2lds16(Bt + boff + k0, ldsB);
        gl2lds16(Bt + boff + (long)64 * K + k0, ldsB + 2048);
        __syncthreads();

        bf16x8 af[4], bfr[4];
#pragma unroll
        for (int mi = 0; mi < 4; ++mi)
            af[mi] = *(const bf16x8*)(As + (wm * 64 + mi * 16 + (lane & 15)) * 32 + (lane >> 4) * 8);
#pragma unroll
        for (int ni = 0; ni < 4; ++ni)
            bfr[ni] = *(const bf16x8*)(Bs + (wn * 64 + ni * 16 + (lane & 15)) * 32 + (lane >> 4) * 8);
#pragma unroll
        for (int mi = 0; mi < 4; ++mi)
#pragma unroll
            for (int ni = 0; ni < 4; ++ni)
                acc[mi][ni] = __builtin_amdgcn_mfma_f32_16x16x32_bf16(af[mi], bfr[ni], acc[mi][ni], 0, 0, 0);
    }

    int cm = (lane >> 4) * 4;
    int cn = lane & 15;
    if (EP == 3) {
#pragma unroll
        for (int mi = 0; mi < 4; ++mi) {
#pragma unroll
            for (int r = 0; r < 4; ++r) {
                float part = 0.f;
#pragma unroll
                for (int ni = 0; ni < 4; ++ni) {
                    int gn = n0 + wn * 64 + ni * 16 + cn;
                    float x = acc[mi][ni][r] + bias[gn];
                    part += gelu_tanh(x) * w2[gn];
                }
                part += __shfl_xor(part, 1, 64);
                part += __shfl_xor(part, 2, 64);
                part += __shfl_xor(part, 4, 64);
                part += __shfl_xor(part, 8, 64);
                if ((lane & 15) == 0)
                    atomicAdd(&logits[m0 + wm * 64 + mi * 16 + cm + r], part);
            }
        }
    } else if (EP == 1) {
#pragma unroll
        for (int mi = 0; mi < 4; ++mi)
#pragma unroll
            for (int ni = 0; ni < 4; ++ni)
#pragma unroll
                for (int r = 0; r < 4; ++r) {
                    int gm = m0 + wm * 64 + mi * 16 + cm + r;
                    int gn = n0 + wn * 64 + ni * 16 + cn;
                    int b = gm >> 9;
                    int row = idxp[gm];
                    float selv = hid[((long)b * TT + row) * DD + gn];
                    Cbf[(long)gm * N + gn] = (__bf16)(selv + acc[mi][ni][r]);
                }
    } else {
#pragma unroll
        for (int mi = 0; mi < 4; ++mi)
#pragma unroll
            for (int ni = 0; ni < 4; ++ni)
#pragma unroll
                for (int r = 0; r < 4; ++r) {
                    int gm = m0 + wm * 64 + mi * 16 + cm + r;
                    int gn = n0 + wn * 64 + ni * 16 + cn;
                    Cbf[(long)gm * N + gn] = (__bf16)acc[mi][ni][r];
                }
    }
}

// ---------------- 2-stream SwiGLU gate/up GEMM on interleaved weights ----------------
// Bt = wgu_t [8192][1024], rows interleaved 16 gate / 16 up per 32.
// Writes act [2048][4096]: pair (ni 0,1) and (ni 2,3) combine in-register.
__global__ __launch_bounds__(256) void gateup2_mfma(const __bf16* __restrict__ Abf,
                                                    const __bf16* __restrict__ Bt,
                                                    __bf16* __restrict__ act) {
    const int K = 1024;
    __shared__ __bf16 As[128 * 32];
    __shared__ __bf16 Bs[128 * 32];
    int tid = threadIdx.x;
    int lane = tid & 63, wave = tid >> 6;
    int wm = wave >> 1, wn = wave & 1;
    int m0 = blockIdx.y * 128, n0 = blockIdx.x * 128;

    f32x4 zv = {0.f, 0.f, 0.f, 0.f};
    f32x4 acc[4][4];
#pragma unroll
    for (int i = 0; i < 4; ++i)
#pragma unroll
        for (int j = 0; j < 4; ++j) acc[i][j] = zv;

    int srow = tid >> 2;
    int scol = (tid & 3) * 8;
    long aoff = (long)(m0 + srow) * K + scol;
    long boff = (long)(n0 + srow) * K + scol;
    __bf16* ldsA = As + wave * 512;
    __bf16* ldsB = Bs + wave * 512;

    for (int k0 = 0; k0 < K; k0 += 32) {
        __syncthreads();
        gl2lds16(Abf + aoff + k0, ldsA);
        gl2lds16(Abf + aoff + (long)64 * K + k0, ldsA + 2048);
        gl2lds16(Bt + boff + k0, ldsB);
        gl2lds16(Bt + boff + (long)64 * K + k0, ldsB + 2048);
        __syncthreads();

        bf16x8 af[4], bfr[4];
#pragma unroll
        for (int mi = 0; mi < 4; ++mi)
            af[mi] = *(const bf16x8*)(As + (wm * 64 + mi * 16 + (lane & 15)) * 32 + (lane >> 4) * 8);
#pragma unroll
        for (int ni = 0; ni < 4; ++ni)
            bfr[ni] = *(const bf16x8*)(Bs + (wn * 64 + ni * 16 + (lane & 15)) * 32 + (lane >> 4) * 8);
#pragma unroll
        for (int mi = 0; mi < 4; ++mi)
#pragma unroll
            for (int ni = 0; ni < 4; ++ni)
                acc[mi][ni] = __builtin_amdgcn_mfma_f32_16x16x32_bf16(af[mi], bfr[ni], acc[mi][ni], 0, 0, 0);
    }

    int cm = (lane >> 4) * 4;
    int cn = lane & 15;
    int colb = ((n0 + wn * 64) >> 1) + cn;   // output col base (pair pi adds 16)
#pragma unroll
    for (int mi = 0; mi < 4; ++mi)
#pragma unroll
        for (int pi = 0; pi < 2; ++pi)
#pragma unroll
            for (int r = 0; r < 4; ++r) {
                int gm = m0 + wm * 64 + mi * 16 + cm + r;
                float g = acc[mi][2 * pi][r];
                float u = acc[mi][2 * pi + 1][r];
                float sl = g / (1.0f + expf(-g));
                act[(long)gm * 4096 + colb + pi * 16] = (__bf16)(sl * u);
            }
}

// ---------------- down proj: split-K=2, bf16 partials ----------------
__global__ __launch_bounds__(256) void down_gemm(const __bf16* __restrict__ act,
                                                 const __bf16* __restrict__ Bt,
                                                 __bf16* __restrict__ p0,
                                                 __bf16* __restrict__ p1) {
    __shared__ __bf16 As[128 * 32];
    __shared__ __bf16 Bs[128 * 32];
    int tid = threadIdx.x;
    int lane = tid & 63, wave = tid >> 6;
    int wm = wave >> 1, wn = wave & 1;
    int m0 = blockIdx.y * 128, n0 = blockIdx.x * 128;
    int z = blockIdx.z;

    f32x4 zv = {0.f, 0.f, 0.f, 0.f};
    f32x4 acc[4][4];
#pragma unroll
    for (int i = 0; i < 4; ++i)
#pragma unroll
        for (int j = 0; j < 4; ++j) acc[i][j] = zv;

    int srow = tid >> 2;
    int scol = (tid & 3) * 8;
    long aoff = (long)(m0 + srow) * 4096 + z * 2048 + scol;
    long boff = (long)(n0 + srow) * 4096 + z * 2048 + scol;
    __bf16* ldsA = As + wave * 512;
    __bf16* ldsB = Bs + wave * 512;

    for (int k0 = 0; k0 < 2048; k0 += 32) {
        __syncthreads();
        gl2lds16(act + aoff + k0, ldsA);
        gl2lds16(act + aoff + (long)64 * 4096 + k0, ldsA + 2048);
        gl2lds16(Bt + boff + k0, ldsB);
        gl2lds16(Bt + boff + (long)64 * 4096 + k0, ldsB + 2048);
        __syncthreads();

        bf16x8 af[4], bfr[4];
#pragma unroll
        for (int mi = 0; mi < 4; ++mi)
            af[mi] = *(const bf16x8*)(As + (wm * 64 + mi * 16 + (lane & 15)) * 32 + (lane >> 4) * 8);
#pragma unroll
        for (int ni = 0; ni < 4; ++ni)
            bfr[ni] = *(const bf16x8*)(Bs + (wn * 64 + ni * 16 + (lane & 15)) * 32 + (lane >> 4) * 8);
#pragma unroll
        for (int mi = 0; mi < 4; ++mi)
#pragma unroll
            for (int ni = 0; ni < 4; ++ni)
                acc[mi][ni] = __builtin_amdgcn_mfma_f32_16x16x32_bf16(af[mi], bfr[ni], acc[mi][ni], 0, 0, 0);
    }

    int cm = (lane >> 4) * 4;
    int cn = lane & 15;
    __bf16* pz = z ? p1 : p0;
#pragma unroll
    for (int mi = 0; mi < 4; ++mi)
#pragma unroll
        for (int ni = 0; ni < 4; ++ni)
#pragma unroll
            for (int r = 0; r < 4; ++r) {
                int gm = m0 + wm * 64 + mi * 16 + cm + r;
                int gn = n0 + wn * 64 + ni * 16 + cn;
                pz[(long)gm * 1024 + gn] = (__bf16)acc[mi][ni][r];
            }
}

// ---------------- combine partials + gated scatter ----------------
__global__ __launch_bounds__(256) void scatter_kernel(const __bf16* __restrict__ p0,
                                                      const __bf16* __restrict__ p1,
                                                      const __bf16* __restrict__ hbf,
                                                      const float* __restrict__ hid,
                                                      const int* __restrict__ idxp,
                                                      const float* __restrict__ gatep,
                                                      float* __restrict__ outp) {
    int m = blockIdx.x;
    int c = threadIdx.x * 4;
    int b = m >> 9;
    int row = idxp[m];
    float gv = gatep[m];
    long pb = (long)m * DD + c;
    bf16x4 v0 = *(const bf16x4*)(p0 + pb);
    bf16x4 v1 = *(const bf16x4*)(p1 + pb);
    bf16x4 hh = *(const bf16x4*)(hbf + pb);
    long ob = ((long)b * TT + row) * DD + c;
    float4 sel = *(const float4*)(hid + ob);
    float4 o;
    o.x = sel.x + gv * ((float)hh[0] + (float)v0[0] + (float)v1[0] - sel.x);
    o.y = sel.y + gv * ((float)hh[1] + (float)v0[1] + (float)v1[1] - sel.y);
    o.z = sel.z + gv * ((float)hh[2] + (float)v0[2] + (float)v1[2] - sel.z);
    o.w = sel.w + gv * ((float)hh[3] + (float)v0[3] + (float)v1[3] - sel.w);
    *(float4*)(outp + ob) = o;
}

// ---------------- rmsnorm: f32-gather or bf16 input, bf16 out ----------------
template <typename TIN>
__global__ __launch_bounds__(256) void rms_kernel(const TIN* __restrict__ src,
                                                  const int* __restrict__ idx,
                                                  const float* __restrict__ gamma,
                                                  __bf16* __restrict__ out) {
    int m = blockIdx.x;
    int tid = threadIdx.x;
    long srow;
    if (idx) {
        int b = m >> 9;
        srow = ((long)b * TT + idx[m]) * DD;
    } else {
        srow = (long)m * DD;
    }
    __shared__ float red[256];
    float v[4];
#pragma unroll
    for (int i = 0; i < 4; ++i) v[i] = (float)src[srow + tid * 4 + i];
    float ss = v[0] * v[0] + v[1] * v[1] + v[2] * v[2] + v[3] * v[3];
    red[tid] = ss;
    __syncthreads();
    for (int s2 = 128; s2 > 0; s2 >>= 1) {
        if (tid < s2) red[tid] += red[tid + s2];
        __syncthreads();
    }
    float r = rsqrtf(red[0] / (float)DD + 1e-6f);
    float4 g4 = *(const float4*)(gamma + tid * 4);
    long obase = (long)m * DD + tid * 4;
    out[obase + 0] = (__bf16)(v[0] * r * g4.x);
    out[obase + 1] = (__bf16)(v[1] * r * g4.y);
    out[obase + 2] = (__bf16)(v[2] * r * g4.z);
    out[obase + 3] = (__bf16)(v[3] * r * g4.w);
}

// ---------------- RoPE on fused qkv (bf16, [M][3072]) ----------------
__global__ __launch_bounds__(512) void rope_kernel(__bf16* __restrict__ qkv,
                                                   const int* __restrict__ idx) {
    int m = blockIdx.x;
    int t = threadIdx.x;
    int h = t >> 5, j = t & 31;
    float pos = (float)idx[m];
    float inv = expf(-((float)(2 * j) / (float)HDD) * 9.210340371976184f);
    float ang = pos * inv;
    float c = cosf(ang), s = sinf(ang);
    long base = (long)m * 3072 + h * HDD + j;
    float x1 = (float)qkv[base], x2 = (float)qkv[base + 32];
    qkv[base] = (__bf16)(x1 * c - x2 * s);
    qkv[base + 32] = (__bf16)(x2 * c + x1 * s);
    long kbase = base + 1024;
    x1 = (float)qkv[kbase]; x2 = (float)qkv[kbase + 32];
    qkv[kbase] = (__bf16)(x1 * c - x2 * s);
    qkv[kbase + 32] = (__bf16)(x2 * c + x1 * s);
}

// ---------------- MFMA flash attention ----------------
__global__ __launch_bounds__(256) void attn_mfma(const __bf16* __restrict__ qkv,
                                                 __bf16* __restrict__ o) {
    int qt = blockIdx.x;
    int bh = blockIdx.y;
    int b = bh >> 4, h = bh & 15;
    int tid = threadIdx.x;
    int lane = tid & 63, w = tid >> 6;
    __shared__ __bf16 Ks[64 * APAD];
    __shared__ __bf16 Vt[64 * APAD];
    __shared__ __bf16 Ps[4][16 * APAD];

    int l15 = lane & 15, l4 = lane >> 4;
    int qrow0 = b * KSEL + qt * 64 + w * 16;
    bf16x8 qf[2];
    {
        long base = ((long)(qrow0 + l15)) * 3072 + h * 64 + l4 * 8;
        qf[0] = *(const bf16x8*)(qkv + base);
        qf[1] = *(const bf16x8*)(qkv + base + 32);
    }
    float m_run[4], l_run[4];
    f32x4 O[4];
#pragma unroll
    for (int r = 0; r < 4; ++r) { m_run[r] = -1e30f; l_run[r] = 0.f; }
    f32x4 zv = {0.f, 0.f, 0.f, 0.f};
#pragma unroll
    for (int ni = 0; ni < 4; ++ni) O[ni] = zv;

    int sr = tid & 63;
    int sg = tid >> 6;
    for (int kt = 0; kt <= qt; ++kt) {
        __syncthreads();
        long kvbase = ((long)(b * KSEL + kt * 64 + sr)) * 3072 + h * 64 + 1024;
        bf16x8 kv0 = *(const bf16x8*)(qkv + kvbase + sg * 16);
        bf16x8 kv1 = *(const bf16x8*)(qkv + kvbase + sg * 16 + 8);
        *(bf16x8*)(Ks + sr * APAD + sg * 16) = kv0;
        *(bf16x8*)(Ks + sr * APAD + sg * 16 + 8) = kv1;
        bf16x8 vv0 = *(const bf16x8*)(qkv + kvbase + 1024 + sg * 16);
        bf16x8 vv1 = *(const bf16x8*)(qkv + kvbase + 1024 + sg * 16 + 8);
#pragma unroll
        for (int i = 0; i < 8; ++i) {
            Vt[(sg * 16 + i) * APAD + sr] = vv0[i];
            Vt[(sg * 16 + 8 + i) * APAD + sr] = vv1[i];
        }
        __syncthreads();

        f32x4 S[4];
#pragma unroll
        for (int ni = 0; ni < 4; ++ni) S[ni] = zv;
#pragma unroll
        for (int ni = 0; ni < 4; ++ni) {
            bf16x8 kf0 = *(const bf16x8*)(Ks + (ni * 16 + l15) * APAD + l4 * 8);
            bf16x8 kf1 = *(const bf16x8*)(Ks + (ni * 16 + l15) * APAD + l4 * 8 + 32);
            S[ni] = __builtin_amdgcn_mfma_f32_16x16x32_bf16(qf[0], kf0, S[ni], 0, 0, 0);
            S[ni] = __builtin_amdgcn_mfma_f32_16x16x32_bf16(qf[1], kf1, S[ni], 0, 0, 0);
        }
        int rowb = qt * 64 + w * 16 + l4 * 4;
#pragma unroll
        for (int r = 0; r < 4; ++r) {
            float sv[4];
            float mx = -1e30f;
#pragma unroll
            for (int ni = 0; ni < 4; ++ni) {
                float x = S[ni][r] * 0.125f;
                int col = kt * 64 + ni * 16 + l15;
                if (col > rowb + r) x = -1e30f;
                sv[ni] = x;
                mx = fmaxf(mx, x);
            }
            mx = fmaxf(mx, __shfl_xor(mx, 1, 64));
            mx = fmaxf(mx, __shfl_xor(mx, 2, 64));
            mx = fmaxf(mx, __shfl_xor(mx, 4, 64));
            mx = fmaxf(mx, __shfl_xor(mx, 8, 64));
            float m_new = fmaxf(m_run[r], mx);
            float alpha = expf(m_run[r] - m_new);
            float ps = 0.f;
#pragma unroll
            for (int ni = 0; ni < 4; ++ni) {
                float e = expf(sv[ni] - m_new);
                sv[ni] = e;
                ps += e;
            }
            ps += __shfl_xor(ps, 1, 64);
            ps += __shfl_xor(ps, 2, 64);
            ps += __shfl_xor(ps, 4, 64);
            ps += __shfl_xor(ps, 8, 64);
            l_run[r] = l_run[r] * alpha + ps;
            m_run[r] = m_new;
#pragma unroll
            for (int ni = 0; ni < 4; ++ni) {
                O[ni][r] *= alpha;
                Ps[w][(l4 * 4 + r) * APAD + ni * 16 + l15] = (__bf16)sv[ni];
            }
        }
#pragma unroll
        for (int ks = 0; ks < 2; ++ks) {
            bf16x8 pf = *(const bf16x8*)(Ps[w] + l15 * APAD + ks * 32 + l4 * 8);
#pragma unroll
            for (int ni = 0; ni < 4; ++ni) {
                bf16x8 vf = *(const bf16x8*)(Vt + (ni * 16 + l15) * APAD + ks * 32 + l4 * 8);
                O[ni] = __builtin_amdgcn_mfma_f32_16x16x32_bf16(pf, vf, O[ni], 0, 0, 0);
            }
        }
    }
    long orow = (long)(b * KSEL + qt * 64 + w * 16);
#pragma unroll
    for (int r = 0; r < 4; ++r) {
        float inv = 1.0f / l_run[r];
#pragma unroll
        for (int ni = 0; ni < 4; ++ni)
            o[(orow + l4 * 4 + r) * DD + h * 64 + ni * 16 + l15] = (__bf16)(O[ni][r] * inv);
    }
}

// ---------------- BCE losses ----------------
__global__ __launch_bounds__(256) void bce_kernel(const float* __restrict__ scores,
                                                  const float* __restrict__ logits,
                                                  const float* __restrict__ flags,
                                                  const float* __restrict__ fc2b,
                                                  float* __restrict__ acc) {
    int i = blockIdx.x * 256 + threadIdx.x;
    int tid = threadIdx.x;
    __shared__ float r0[256];
    __shared__ float r1[256];
    float tgt = flags[i];
    r0[tid] = bce_term(scores[i], tgt);
    r1[tid] = bce_term(logits[i] + fc2b[0], tgt);
    __syncthreads();
    for (int s2 = 128; s2 > 0; s2 >>= 1) {
        if (tid < s2) { r0[tid] += r0[tid + s2]; r1[tid] += r1[tid + s2]; }
        __syncthreads();
    }
    if (tid == 0) {
        atomicAdd(acc + 0, r0[0]);
        atomicAdd(acc + 1, r1[0]);
    }
}

__global__ void finalize_kernel(const float* __restrict__ acc, float* __restrict__ out) {
    out[0] = (acc[0] / (float)BT) * 0.01f + (acc[1] / (float)BT) * 0.01f;
}

extern "C" void kernel_launch(void* const* d_in, const int* in_sizes, int n_in,
                              void* d_out, int out_size, void* d_ws, size_t ws_size,
                              hipStream_t stream) {
    const float* hidden = (const float*)d_in[0];
    const float* router_w = (const float*)d_in[1];
    const float* fc1_w = (const float*)d_in[2];
    const float* fc1_b = (const float*)d_in[3];
    const float* fc2_w = (const float*)d_in[4];
    const float* fc2_b = (const float*)d_in[5];
    const float* ln1_g = (const float*)d_in[6];
    const float* ln2_g = (const float*)d_in[7];
    const float* wq = (const float*)d_in[8];
    const float* wk = (const float*)d_in[9];
    const float* wv = (const float*)d_in[10];
    const float* wo = (const float*)d_in[11];
    const float* w_gate = (const float*)d_in[12];
    const float* w_up = (const float*)d_in[13];
    const float* w_down = (const float*)d_in[14];

    float* out = (float*)d_out;
    char* wsb = (char*)d_ws;

    // ---- workspace layout (peak 52.75 MiB; 54.75 MiB proven in R3) ----
    float* scores = (float*)(wsb);                 // 64K
    float* flags  = (float*)(wsb + 0x10000);       // 64K
    float* logits = (float*)(wsb + 0x20000);       // 64K
    int*   idx    = (int*)  (wsb + 0x30000);       // 8K
    float* gate   = (float*)(wsb + 0x32000);       // 8K
    float* acc    = (float*)(wsb + 0x34000);
    __bf16* fc1_t  = (__bf16*)(wsb + 0x40000);     // [256][1024]  512K
    __bf16* wo_t   = (__bf16*)(wsb + 0xC0000);     // [1024][1024] 2M
    __bf16* wqkv_t = (__bf16*)(wsb + 0x2C0000);    // [3072][1024] 6M -> 0x8C0000
    // region A: hidden_bf 32M (fused_pass -> predictor), then reused:
    __bf16* hidden_bf = (__bf16*)(wsb + 0x8C0000);   // -> 0x28C0000
    __bf16* qkv    = (__bf16*)(wsb + 0x8C0000);      // 12M (qkv GEMM -> attn)
    __bf16* a_bf   = (__bf16*)(wsb + 0x14C0000);     // 4M  (rms1 -> qkv GEMM)
    __bf16* act_bf = (__bf16*)(wsb + 0x8C0000);      // 16M (gateup -> down)
    __bf16* att_bf = (__bf16*)(wsb + 0x18C0000);     // 4M  (attn -> wo)
    __bf16* h_bf   = (__bf16*)(wsb + 0x1CC0000);     // 4M  (wo -> scatter)
    __bf16* m_bf   = (__bf16*)(wsb + 0x20C0000);     // 4M  (rms2 -> gateup)
    __bf16* wgu_t  = (__bf16*)(wsb + 0x24C0000);     // 16M (cast -> gateup) -> 0x34C0000
    __bf16* wd_t   = (__bf16*)(wsb + 0x24C0000);     // 8M  (cast after gateup -> down)
    __bf16* p0     = (__bf16*)(wsb + 0x2CC0000);     // 4M  (down -> scatter)
    __bf16* p1     = (__bf16*)(wsb + 0x30C0000);     // 4M  -> 0x34C0000

    // 1. zero accumulators
    hipMemsetAsync(acc, 0, 2 * sizeof(float), stream);
    hipMemsetAsync(logits, 0, BT * sizeof(float), stream);

    // 2. early weight casts (fc1, wq, wk, wv, wo) in one kernel
    {
        CPack p;
        p.nd = 5;
        p.d[0] = {fc1_w, fc1_t, DD, 256, 0, 0};
        p.d[1] = {wq, wqkv_t, DD, DD, 256, 0};
        p.d[2] = {wk, wqkv_t + (size_t)1024 * 1024, DD, DD, 1280, 0};
        p.d[3] = {wv, wqkv_t + (size_t)2048 * 1024, DD, DD, 2304, 0};
        p.d[4] = {wo, wo_t, DD, DD, 3328, 0};
        cast_multi<<<4352, 256, 0, stream>>>(p);
    }

    // 3. fused passthrough copy + bf16 cast + router scores; top-k
    fused_pass<<<BT / 4, 256, 0, stream>>>(hidden, router_w, out, hidden_bf, scores);
    topk_kernel<<<BB, 1024, 0, stream>>>(scores, flags, idx, gate);

    // 4. predictor GEMM + BCE
    mfma_gemm<3><<<dim3(2, BT / 128), 256, 0, stream>>>(
        hidden_bf, fc1_t, BT, 256, DD, nullptr, nullptr, nullptr,
        fc1_b, fc2_w, logits);
    bce_kernel<<<BT / 256, 256, 0, stream>>>(scores, logits, flags, fc2_b, acc);

    // 5. gather + rmsnorm1 -> a_bf
    rms_kernel<float><<<MTOK, 256, 0, stream>>>(hidden, idx, ln1_g, a_bf);

    // 6. fused qkv projection (plain EP=0) + separate RoPE
    mfma_gemm<0><<<dim3(3072 / 128, MTOK / 128), 256, 0, stream>>>(
        a_bf, wqkv_t, MTOK, 3072, DD, qkv, nullptr, nullptr,
        nullptr, nullptr, nullptr);
    rope_kernel<<<MTOK, 512, 0, stream>>>(qkv, idx);

    // 7. MFMA flash attention
    attn_mfma<<<dim3(KSEL / 64, BB * NHH), 256, 0, stream>>>(qkv, att_bf);

    // 8. cast wg/wu interleaved -> wgu_t
    {
        CPack p;
        p.nd = 2;
        p.d[0] = {w_gate, wgu_t, DD, FF, 0, 1};
        p.d[1] = {w_up,   wgu_t, DD, FF, 4096, 2};
        cast_multi<<<8192, 256, 0, stream>>>(p);
    }

    // 9. Wo + residual -> h_bf
    mfma_gemm<1><<<dim3(DD / 128, MTOK / 128), 256, 0, stream>>>(
        att_bf, wo_t, MTOK, DD, DD, h_bf, hidden, idx,
        nullptr, nullptr, nullptr);

    // 10. rmsnorm2 -> m_bf
    rms_kernel<__bf16><<<MTOK, 256, 0, stream>>>(h_bf, nullptr, ln2_g, m_bf);

    // 11. 2-stream SwiGLU gate/up (interleaved N=8192) -> act_bf [2048][4096]
    gateup2_mfma<<<dim3(8192 / 128, MTOK / 128), 256, 0, stream>>>(m_bf, wgu_t, act_bf);

    // 12. cast w_down -> wd_t (wgu dead)
    {
        CPack p;
        p.nd = 1;
        p.d[0] = {w_down, wd_t, FF, DD, 0, 0};
        cast_multi<<<4096, 256, 0, stream>>>(p);
    }

    // 13. down proj split-K=2 -> bf16 partials
    down_gemm<<<dim3(DD / 128, MTOK / 128, 2), 256, 0, stream>>>(act_bf, wd_t, p0, p1);

    // 14. combine partials + gated scatter into out
    scatter_kernel<<<MTOK, 256, 0, stream>>>(p0, p1, h_bf, hidden, idx, gate, out);

    // 15. aux scalar
    finalize_kernel<<<1, 1, 0, stream>>>(acc, out + (size_t)BT * DD);
}

// Round 6
// 459.091 us; speedup vs baseline: 1.4075x; 1.1425x over previous
//
#include <hip/hip_runtime.h>
#include <math.h>

#define BB 4
#define TT 4096
#define DD 1024
#define FF 4096
#define NHH 16
#define HDD 64
#define KSEL 512
#define BT (BB*TT)        // 16384
#define MTOK (BB*KSEL)    // 2048
#define APAD 72

typedef __bf16 bf16x8 __attribute__((ext_vector_type(8)));
typedef __bf16 bf16x4 __attribute__((ext_vector_type(4)));
typedef float  f32x4  __attribute__((ext_vector_type(4)));

__device__ __forceinline__ void gl2lds16(const void* g, void* l) {
    __builtin_amdgcn_global_load_lds(
        (const __attribute__((address_space(1))) void*)g,
        (__attribute__((address_space(3))) void*)l,
        16, 0, 0);
}

__device__ __forceinline__ float gelu_tanh(float x) {
    return 0.5f * x * (1.0f + tanhf(0.7978845608028654f * (x + 0.044715f * x * x * x)));
}
__device__ __forceinline__ float bce_term(float x, float t) {
    return fmaxf(x, 0.f) - x * t + log1pf(expf(-fabsf(x)));
}

// ---------------- fused: passthrough copy + bf16 cast + router scores ----------------
__global__ __launch_bounds__(256) void fused_pass(const float* __restrict__ hs,
                                                  const float* __restrict__ rw,
                                                  float* __restrict__ outp,
                                                  __bf16* __restrict__ hbf,
                                                  float* __restrict__ scores) {
    int wave = threadIdx.x >> 6, lane = threadIdx.x & 63;
    int row = blockIdx.x * 4 + wave;
    long base = (long)row * DD;
    float s = 0.f;
#pragma unroll
    for (int it = 0; it < 4; ++it) {
        int c = it * 256 + lane * 4;
        float4 v = *(const float4*)(hs + base + c);
        *(float4*)(outp + base + c) = v;
        float4 r4 = *(const float4*)(rw + c);
        s += v.x * r4.x + v.y * r4.y + v.z * r4.z + v.w * r4.w;
        bf16x4 b4 = {(__bf16)v.x, (__bf16)v.y, (__bf16)v.z, (__bf16)v.w};
        *(bf16x4*)(hbf + base + c) = b4;
    }
    for (int off = 32; off > 0; off >>= 1) s += __shfl_down(s, off, 64);
    if (lane == 0) scores[row] = s;
}

// ---------------- top-k per batch: 3-level radix select ----------------
// Replicates jax.lax.top_k (value desc, index asc tie-break) + ascending idx sort.
__global__ __launch_bounds__(1024) void topk_radix(const float* __restrict__ scores,
                                                   float* __restrict__ flags,
                                                   int* __restrict__ idx_out,
                                                   float* __restrict__ gate_out) {
    int b = blockIdx.x, tid = threadIdx.x;
    int lane = tid & 63, wid = tid >> 6;
    __shared__ unsigned ku[TT];          // 16 KB ordered keys
    __shared__ unsigned hist[4096];      // 16 KB
    __shared__ unsigned cand[4096];      // 16 KB (worst-case capacity)
    __shared__ unsigned char selb[TT];   // 4 KB
    __shared__ unsigned wsum[16];
    __shared__ int vars[8];
    const float* sc = scores + b * TT;
    const unsigned K = KSEL;

    for (int i = tid; i < TT; i += 1024) {
        unsigned u = __float_as_uint(sc[i]);
        ku[i] = u ^ ((u & 0x80000000u) ? 0xFFFFFFFFu : 0x80000000u);
    }
    for (int j = tid; j < 4096; j += 1024) hist[j] = 0;
    __syncthreads();
    for (int i = tid; i < TT; i += 1024) atomicAdd(&hist[ku[i] >> 20], 1u);
    __syncthreads();

    // ---- level 1: suffix scan over 4096 buckets, find B1 ----
    unsigned c0 = hist[4 * tid], c1 = hist[4 * tid + 1];
    unsigned c2 = hist[4 * tid + 2], c3 = hist[4 * tid + 3];
    unsigned l3 = c3, l2 = c2 + l3, l1 = c1 + l2, l0 = c0 + l1;
    unsigned v = l0;
    for (int off = 1; off < 64; off <<= 1) {
        unsigned o = (unsigned)__shfl_down((int)v, off, 64);
        if (lane + off < 64) v += o;
    }
    if (lane == 0) wsum[wid] = v;
    __syncthreads();
    if (tid < 16) {
        unsigned s = wsum[tid];
        for (int off = 1; off < 16; off <<= 1) {
            unsigned o = (unsigned)__shfl_down((int)s, off, 64);
            if (tid + off < 16) s += o;
        }
        wsum[tid] = s;
    }
    __syncthreads();
    unsigned wavetail = (wid + 1 < 16) ? wsum[wid + 1] : 0u;
    unsigned tail = v + wavetail - l0;          // suffix over buckets >= 4*(tid+1)
    unsigned S0 = l0 + tail, S1 = l1 + tail, S2 = l2 + tail, S3 = l3 + tail;
    if (S0 >= K && S1 < K)   { vars[0] = 4 * tid;     vars[1] = (int)S1; }
    if (S1 >= K && S2 < K)   { vars[0] = 4 * tid + 1; vars[1] = (int)S2; }
    if (S2 >= K && S3 < K)   { vars[0] = 4 * tid + 2; vars[1] = (int)S3; }
    if (S3 >= K && tail < K) { vars[0] = 4 * tid + 3; vars[1] = (int)tail; }
    __syncthreads();
    int B1 = vars[0];
    unsigned need = K - (unsigned)vars[1];

    // ---- level 2: next 12 bits within bucket B1 ----
    for (int j = tid; j < 4096; j += 1024) hist[j] = 0;
    __syncthreads();
    for (int i = tid; i < TT; i += 1024)
        if ((int)(ku[i] >> 20) == B1) atomicAdd(&hist[(ku[i] >> 8) & 0xFFFu], 1u);
    __syncthreads();
    c0 = hist[4 * tid]; c1 = hist[4 * tid + 1];
    c2 = hist[4 * tid + 2]; c3 = hist[4 * tid + 3];
    l3 = c3; l2 = c2 + l3; l1 = c1 + l2; l0 = c0 + l1;
    v = l0;
    for (int off = 1; off < 64; off <<= 1) {
        unsigned o = (unsigned)__shfl_down((int)v, off, 64);
        if (lane + off < 64) v += o;
    }
    if (lane == 0) wsum[wid] = v;
    __syncthreads();
    if (tid < 16) {
        unsigned s = wsum[tid];
        for (int off = 1; off < 16; off <<= 1) {
            unsigned o = (unsigned)__shfl_down((int)s, off, 64);
            if (tid + off < 16) s += o;
        }
        wsum[tid] = s;
    }
    if (tid == 0) vars[4] = 0;
    __syncthreads();
    wavetail = (wid + 1 < 16) ? wsum[wid + 1] : 0u;
    tail = v + wavetail - l0;
    S0 = l0 + tail; S1 = l1 + tail; S2 = l2 + tail; S3 = l3 + tail;
    if (S0 >= need && S1 < need)   { vars[2] = 4 * tid;     vars[3] = (int)S1; }
    if (S1 >= need && S2 < need)   { vars[2] = 4 * tid + 1; vars[3] = (int)S2; }
    if (S2 >= need && S3 < need)   { vars[2] = 4 * tid + 2; vars[3] = (int)S3; }
    if (S3 >= need && tail < need) { vars[2] = 4 * tid + 3; vars[3] = (int)tail; }
    __syncthreads();
    int B2 = vars[2];
    unsigned need2 = need - (unsigned)vars[3];

    // ---- base selection + candidate collection ----
    for (int i = tid; i < TT; i += 1024) {
        unsigned k = ku[i];
        int top = (int)(k >> 20);
        unsigned char s = 0;
        if (top > B1) s = 1;
        else if (top == B1) {
            int sub = (int)((k >> 8) & 0xFFFu);
            if (sub > B2) s = 1;
            else if (sub == B2) {
                unsigned pos = atomicAdd((unsigned*)&vars[4], 1u);
                cand[pos] = ((k & 0xFFu) << 12) | (unsigned)(4095 - i);
            }
        }
        selb[i] = s;
    }
    __syncthreads();
    // ---- rank candidates: key desc == value desc then index asc ----
    int cn = vars[4];
    for (int i = tid; i < cn; i += 1024) {
        unsigned key = cand[i];
        unsigned rank = 0;
        for (int j = 0; j < cn; ++j) rank += (cand[j] > key) ? 1u : 0u;
        if (rank < need2) selb[4095 - (int)(key & 0xFFFu)] = 1;
    }
    __syncthreads();

    // ---- flags + ascending-index compaction ----
    int i0 = 4 * tid;
    int s0 = selb[i0], s1 = selb[i0 + 1], s2 = selb[i0 + 2], s3 = selb[i0 + 3];
    flags[b * TT + i0]     = (float)s0;
    flags[b * TT + i0 + 1] = (float)s1;
    flags[b * TT + i0 + 2] = (float)s2;
    flags[b * TT + i0 + 3] = (float)s3;
    int totalv = s0 + s1 + s2 + s3;
    unsigned pv = (unsigned)totalv;
    for (int off = 1; off < 64; off <<= 1) {
        unsigned o = (unsigned)__shfl_up((int)pv, off, 64);
        if (lane >= off) pv += o;
    }
    if (lane == 63) wsum[wid] = pv;
    __syncthreads();
    if (tid < 16) {
        unsigned s = wsum[tid];
        for (int off = 1; off < 16; off <<= 1) {
            unsigned o = (unsigned)__shfl_up((int)s, off, 64);
            if (tid >= off) s += o;
        }
        wsum[tid] = s;
    }
    __syncthreads();
    unsigned head = (wid > 0) ? wsum[wid - 1] : 0u;
    int pos = (int)(pv + head) - totalv;
    if (s0) { idx_out[b * KSEL + pos] = i0;     gate_out[b * KSEL + pos] = 1.f / (1.f + expf(-sc[i0]));     pos++; }
    if (s1) { idx_out[b * KSEL + pos] = i0 + 1; gate_out[b * KSEL + pos] = 1.f / (1.f + expf(-sc[i0 + 1])); pos++; }
    if (s2) { idx_out[b * KSEL + pos] = i0 + 2; gate_out[b * KSEL + pos] = 1.f / (1.f + expf(-sc[i0 + 2])); pos++; }
    if (s3) { idx_out[b * KSEL + pos] = i0 + 3; gate_out[b * KSEL + pos] = 1.f / (1.f + expf(-sc[i0 + 3])); }
}

// ---------------- multi-weight cast+transpose: f32 [K][N] -> bf16 [N][K] ----------------
// ilv: 0 none; 1 gate-interleave (row = (n>>4)*32 + (n&15)); 2 up (+16)
struct CDesc { const float* src; __bf16* dst; int K, N, start, ilv; };
struct CPack { CDesc d[5]; int nd; };

__global__ __launch_bounds__(256) void cast_multi(CPack p) {
    int bid = blockIdx.x, di = 0;
    while (di + 1 < p.nd && bid >= p.d[di + 1].start) ++di;
    const float* src = p.d[di].src;
    __bf16* dst = p.d[di].dst;
    int K = p.d[di].K, N = p.d[di].N, ilv = p.d[di].ilv;
    int local = bid - p.d[di].start;
    int tn = N >> 5;
    int n0 = (local % tn) * 32, k0 = (local / tn) * 32;
    __shared__ float tile[32][33];
    int tx = threadIdx.x & 31, ty = threadIdx.x >> 5;
#pragma unroll
    for (int i = 0; i < 32; i += 8)
        tile[ty + i][tx] = src[(long)(k0 + ty + i) * N + n0 + tx];
    __syncthreads();
#pragma unroll
    for (int i = 0; i < 32; i += 8) {
        int n = n0 + ty + i;
        int orow = n;
        if (ilv) orow = ((n >> 4) << 5) + (n & 15) + ((ilv == 2) ? 16 : 0);
        dst[(long)orow * K + k0 + tx] = (__bf16)tile[tx][ty + i];
    }
}

// ---------------- MFMA GEMM: A[MxK] bf16, Bt[NxK] bf16, 128x128 tile ----------------
// EP 0: Cbf = A@B
// EP 1: Cbf = gather(hid,idx) + A@B            [wo + residual]
// EP 3: logits[row] += sum_n gelu(A@B+bias)*w2 [predictor]
template <int EP>
__global__ __launch_bounds__(256) void mfma_gemm(const __bf16* __restrict__ Abf,
                                                 const __bf16* __restrict__ Bt,
                                                 int M, int N, int K,
                                                 __bf16* __restrict__ Cbf,
                                                 const float* __restrict__ hid,
                                                 const int* __restrict__ idxp,
                                                 const float* __restrict__ bias,
                                                 const float* __restrict__ w2,
                                                 float* __restrict__ logits) {
    __shared__ __bf16 As[128 * 32];
    __shared__ __bf16 Bs[128 * 32];
    int tid = threadIdx.x;
    int lane = tid & 63, wave = tid >> 6;
    int wm = wave >> 1, wn = wave & 1;
    int m0 = blockIdx.y * 128, n0 = blockIdx.x * 128;

    f32x4 zv = {0.f, 0.f, 0.f, 0.f};
    f32x4 acc[4][4];
#pragma unroll
    for (int i = 0; i < 4; ++i)
#pragma unroll
        for (int j = 0; j < 4; ++j) acc[i][j] = zv;

    int srow = tid >> 2;
    int scol = (tid & 3) * 8;
    long aoff = (long)(m0 + srow) * K + scol;
    long boff = (long)(n0 + srow) * K + scol;
    __bf16* ldsA = As + wave * 512;
    __bf16* ldsB = Bs + wave * 512;

    for (int k0 = 0; k0 < K; k0 += 32) {
        __syncthreads();
        gl2lds16(Abf + aoff + k0, ldsA);
        gl2lds16(Abf + aoff + (long)64 * K + k0, ldsA + 2048);
        gl2lds16(Bt + boff + k0, ldsB);
        gl2lds16(Bt + boff + (long)64 * K + k0, ldsB + 2048);
        __syncthreads();

        bf16x8 af[4], bfr[4];
#pragma unroll
        for (int mi = 0; mi < 4; ++mi)
            af[mi] = *(const bf16x8*)(As + (wm * 64 + mi * 16 + (lane & 15)) * 32 + (lane >> 4) * 8);
#pragma unroll
        for (int ni = 0; ni < 4; ++ni)
            bfr[ni] = *(const bf16x8*)(Bs + (wn * 64 + ni * 16 + (lane & 15)) * 32 + (lane >> 4) * 8);
#pragma unroll
        for (int mi = 0; mi < 4; ++mi)
#pragma unroll
            for (int ni = 0; ni < 4; ++ni)
                acc[mi][ni] = __builtin_amdgcn_mfma_f32_16x16x32_bf16(af[mi], bfr[ni], acc[mi][ni], 0, 0, 0);
    }

    int cm = (lane >> 4) * 4;
    int cn = lane & 15;
    if (EP == 3) {
#pragma unroll
        for (int mi = 0; mi < 4; ++mi) {
#pragma unroll
            for (int r = 0; r < 4; ++r) {
                float part = 0.f;
#pragma unroll
                for (int ni = 0; ni < 4; ++ni) {
                    int gn = n0 + wn * 64 + ni * 16 + cn;
                    float x = acc[mi][ni][r] + bias[gn];
                    part += gelu_tanh(x) * w2[gn];
                }
                part += __shfl_xor(part, 1, 64);
                part += __shfl_xor(part, 2, 64);
                part += __shfl_xor(part, 4, 64);
                part += __shfl_xor(part, 8, 64);
                if ((lane & 15) == 0)
                    atomicAdd(&logits[m0 + wm * 64 + mi * 16 + cm + r], part);
            }
        }
    } else if (EP == 1) {
#pragma unroll
        for (int mi = 0; mi < 4; ++mi)
#pragma unroll
            for (int ni = 0; ni < 4; ++ni)
#pragma unroll
                for (int r = 0; r < 4; ++r) {
                    int gm = m0 + wm * 64 + mi * 16 + cm + r;
                    int gn = n0 + wn * 64 + ni * 16 + cn;
                    int b = gm >> 9;
                    int row = idxp[gm];
                    float selv = hid[((long)b * TT + row) * DD + gn];
                    Cbf[(long)gm * N + gn] = (__bf16)(selv + acc[mi][ni][r]);
                }
    } else {
#pragma unroll
        for (int mi = 0; mi < 4; ++mi)
#pragma unroll
            for (int ni = 0; ni < 4; ++ni)
#pragma unroll
                for (int r = 0; r < 4; ++r) {
                    int gm = m0 + wm * 64 + mi * 16 + cm + r;
                    int gn = n0 + wn * 64 + ni * 16 + cn;
                    Cbf[(long)gm * N + gn] = (__bf16)acc[mi][ni][r];
                }
    }
}

// ---------------- 2-stream SwiGLU gate/up GEMM on interleaved weights ----------------
__global__ __launch_bounds__(256) void gateup2_mfma(const __bf16* __restrict__ Abf,
                                                    const __bf16* __restrict__ Bt,
                                                    __bf16* __restrict__ act) {
    const int K = 1024;
    __shared__ __bf16 As[128 * 32];
    __shared__ __bf16 Bs[128 * 32];
    int tid = threadIdx.x;
    int lane = tid & 63, wave = tid >> 6;
    int wm = wave >> 1, wn = wave & 1;
    int m0 = blockIdx.y * 128, n0 = blockIdx.x * 128;

    f32x4 zv = {0.f, 0.f, 0.f, 0.f};
    f32x4 acc[4][4];
#pragma unroll
    for (int i = 0; i < 4; ++i)
#pragma unroll
        for (int j = 0; j < 4; ++j) acc[i][j] = zv;

    int srow = tid >> 2;
    int scol = (tid & 3) * 8;
    long aoff = (long)(m0 + srow) * K + scol;
    long boff = (long)(n0 + srow) * K + scol;
    __bf16* ldsA = As + wave * 512;
    __bf16* ldsB = Bs + wave * 512;

    for (int k0 = 0; k0 < K; k0 += 32) {
        __syncthreads();
        gl2lds16(Abf + aoff + k0, ldsA);
        gl2lds16(Abf + aoff + (long)64 * K + k0, ldsA + 2048);
        gl2lds16(Bt + boff + k0, ldsB);
        gl2lds16(Bt + boff + (long)64 * K + k0, ldsB + 2048);
        __syncthreads();

        bf16x8 af[4], bfr[4];
#pragma unroll
        for (int mi = 0; mi < 4; ++mi)
            af[mi] = *(const bf16x8*)(As + (wm * 64 + mi * 16 + (lane & 15)) * 32 + (lane >> 4) * 8);
#pragma unroll
        for (int ni = 0; ni < 4; ++ni)
            bfr[ni] = *(const bf16x8*)(Bs + (wn * 64 + ni * 16 + (lane & 15)) * 32 + (lane >> 4) * 8);
#pragma unroll
        for (int mi = 0; mi < 4; ++mi)
#pragma unroll
            for (int ni = 0; ni < 4; ++ni)
                acc[mi][ni] = __builtin_amdgcn_mfma_f32_16x16x32_bf16(af[mi], bfr[ni], acc[mi][ni], 0, 0, 0);
    }

    int cm = (lane >> 4) * 4;
    int cn = lane & 15;
    int colb = ((n0 + wn * 64) >> 1) + cn;
#pragma unroll
    for (int mi = 0; mi < 4; ++mi)
#pragma unroll
        for (int pi = 0; pi < 2; ++pi)
#pragma unroll
            for (int r = 0; r < 4; ++r) {
                int gm = m0 + wm * 64 + mi * 16 + cm + r;
                float g = acc[mi][2 * pi][r];
                float u = acc[mi][2 * pi + 1][r];
                float sl = g / (1.0f + expf(-g));
                act[(long)gm * 4096 + colb + pi * 16] = (__bf16)(sl * u);
            }
}

// ---------------- down proj: split-K=2, bf16 partials ----------------
__global__ __launch_bounds__(256) void down_gemm(const __bf16* __restrict__ act,
                                                 const __bf16* __restrict__ Bt,
                                                 __bf16* __restrict__ p0,
                                                 __bf16* __restrict__ p1) {
    __shared__ __bf16 As[128 * 32];
    __shared__ __bf16 Bs[128 * 32];
    int tid = threadIdx.x;
    int lane = tid & 63, wave = tid >> 6;
    int wm = wave >> 1, wn = wave & 1;
    int m0 = blockIdx.y * 128, n0 = blockIdx.x * 128;
    int z = blockIdx.z;

    f32x4 zv = {0.f, 0.f, 0.f, 0.f};
    f32x4 acc[4][4];
#pragma unroll
    for (int i = 0; i < 4; ++i)
#pragma unroll
        for (int j = 0; j < 4; ++j) acc[i][j] = zv;

    int srow = tid >> 2;
    int scol = (tid & 3) * 8;
    long aoff = (long)(m0 + srow) * 4096 + z * 2048 + scol;
    long boff = (long)(n0 + srow) * 4096 + z * 2048 + scol;
    __bf16* ldsA = As + wave * 512;
    __bf16* ldsB = Bs + wave * 512;

    for (int k0 = 0; k0 < 2048; k0 += 32) {
        __syncthreads();
        gl2lds16(act + aoff + k0, ldsA);
        gl2lds16(act + aoff + (long)64 * 4096 + k0, ldsA + 2048);
        gl2lds16(Bt + boff + k0, ldsB);
        gl2lds16(Bt + boff + (long)64 * 4096 + k0, ldsB + 2048);
        __syncthreads();

        bf16x8 af[4], bfr[4];
#pragma unroll
        for (int mi = 0; mi < 4; ++mi)
            af[mi] = *(const bf16x8*)(As + (wm * 64 + mi * 16 + (lane & 15)) * 32 + (lane >> 4) * 8);
#pragma unroll
        for (int ni = 0; ni < 4; ++ni)
            bfr[ni] = *(const bf16x8*)(Bs + (wn * 64 + ni * 16 + (lane & 15)) * 32 + (lane >> 4) * 8);
#pragma unroll
        for (int mi = 0; mi < 4; ++mi)
#pragma unroll
            for (int ni = 0; ni < 4; ++ni)
                acc[mi][ni] = __builtin_amdgcn_mfma_f32_16x16x32_bf16(af[mi], bfr[ni], acc[mi][ni], 0, 0, 0);
    }

    int cm = (lane >> 4) * 4;
    int cn = lane & 15;
    __bf16* pz = z ? p1 : p0;
#pragma unroll
    for (int mi = 0; mi < 4; ++mi)
#pragma unroll
        for (int ni = 0; ni < 4; ++ni)
#pragma unroll
            for (int r = 0; r < 4; ++r) {
                int gm = m0 + wm * 64 + mi * 16 + cm + r;
                int gn = n0 + wn * 64 + ni * 16 + cn;
                pz[(long)gm * 1024 + gn] = (__bf16)acc[mi][ni][r];
            }
}

// ---------------- combine partials + gated scatter ----------------
__global__ __launch_bounds__(256) void scatter_kernel(const __bf16* __restrict__ p0,
                                                      const __bf16* __restrict__ p1,
                                                      const __bf16* __restrict__ hbf,
                                                      const float* __restrict__ hid,
                                                      const int* __restrict__ idxp,
                                                      const float* __restrict__ gatep,
                                                      float* __restrict__ outp) {
    int m = blockIdx.x;
    int c = threadIdx.x * 4;
    int b = m >> 9;
    int row = idxp[m];
    float gv = gatep[m];
    long pb = (long)m * DD + c;
    bf16x4 v0 = *(const bf16x4*)(p0 + pb);
    bf16x4 v1 = *(const bf16x4*)(p1 + pb);
    bf16x4 hh = *(const bf16x4*)(hbf + pb);
    long ob = ((long)b * TT + row) * DD + c;
    float4 sel = *(const float4*)(hid + ob);
    float4 o;
    o.x = sel.x + gv * ((float)hh[0] + (float)v0[0] + (float)v1[0] - sel.x);
    o.y = sel.y + gv * ((float)hh[1] + (float)v0[1] + (float)v1[1] - sel.y);
    o.z = sel.z + gv * ((float)hh[2] + (float)v0[2] + (float)v1[2] - sel.z);
    o.w = sel.w + gv * ((float)hh[3] + (float)v0[3] + (float)v1[3] - sel.w);
    *(float4*)(outp + ob) = o;
}

// ---------------- rmsnorm: f32-gather or bf16 input, bf16 out ----------------
template <typename TIN>
__global__ __launch_bounds__(256) void rms_kernel(const TIN* __restrict__ src,
                                                  const int* __restrict__ idx,
                                                  const float* __restrict__ gamma,
                                                  __bf16* __restrict__ out) {
    int m = blockIdx.x;
    int tid = threadIdx.x;
    long srow;
    if (idx) {
        int b = m >> 9;
        srow = ((long)b * TT + idx[m]) * DD;
    } else {
        srow = (long)m * DD;
    }
    __shared__ float red[256];
    float v[4];
#pragma unroll
    for (int i = 0; i < 4; ++i) v[i] = (float)src[srow + tid * 4 + i];
    float ss = v[0] * v[0] + v[1] * v[1] + v[2] * v[2] + v[3] * v[3];
    red[tid] = ss;
    __syncthreads();
    for (int s2 = 128; s2 > 0; s2 >>= 1) {
        if (tid < s2) red[tid] += red[tid + s2];
        __syncthreads();
    }
    float r = rsqrtf(red[0] / (float)DD + 1e-6f);
    float4 g4 = *(const float4*)(gamma + tid * 4);
    long obase = (long)m * DD + tid * 4;
    out[obase + 0] = (__bf16)(v[0] * r * g4.x);
    out[obase + 1] = (__bf16)(v[1] * r * g4.y);
    out[obase + 2] = (__bf16)(v[2] * r * g4.z);
    out[obase + 3] = (__bf16)(v[3] * r * g4.w);
}

// ---------------- RoPE on fused qkv (bf16, [M][3072]) ----------------
__global__ __launch_bounds__(512) void rope_kernel(__bf16* __restrict__ qkv,
                                                   const int* __restrict__ idx) {
    int m = blockIdx.x;
    int t = threadIdx.x;
    int h = t >> 5, j = t & 31;
    float pos = (float)idx[m];
    float inv = expf(-((float)(2 * j) / (float)HDD) * 9.210340371976184f);
    float ang = pos * inv;
    float c = cosf(ang), s = sinf(ang);
    long base = (long)m * 3072 + h * HDD + j;
    float x1 = (float)qkv[base], x2 = (float)qkv[base + 32];
    qkv[base] = (__bf16)(x1 * c - x2 * s);
    qkv[base + 32] = (__bf16)(x2 * c + x1 * s);
    long kbase = base + 1024;
    x1 = (float)qkv[kbase]; x2 = (float)qkv[kbase + 32];
    qkv[kbase] = (__bf16)(x1 * c - x2 * s);
    qkv[kbase + 32] = (__bf16)(x2 * c + x1 * s);
}

// ---------------- MFMA flash attention ----------------
__global__ __launch_bounds__(256) void attn_mfma(const __bf16* __restrict__ qkv,
                                                 __bf16* __restrict__ o) {
    int qt = blockIdx.x;
    int bh = blockIdx.y;
    int b = bh >> 4, h = bh & 15;
    int tid = threadIdx.x;
    int lane = tid & 63, w = tid >> 6;
    __shared__ __bf16 Ks[64 * APAD];
    __shared__ __bf16 Vt[64 * APAD];
    __shared__ __bf16 Ps[4][16 * APAD];

    int l15 = lane & 15, l4 = lane >> 4;
    int qrow0 = b * KSEL + qt * 64 + w * 16;
    bf16x8 qf[2];
    {
        long base = ((long)(qrow0 + l15)) * 3072 + h * 64 + l4 * 8;
        qf[0] = *(const bf16x8*)(qkv + base);
        qf[1] = *(const bf16x8*)(qkv + base + 32);
    }
    float m_run[4], l_run[4];
    f32x4 O[4];
#pragma unroll
    for (int r = 0; r < 4; ++r) { m_run[r] = -1e30f; l_run[r] = 0.f; }
    f32x4 zv = {0.f, 0.f, 0.f, 0.f};
#pragma unroll
    for (int ni = 0; ni < 4; ++ni) O[ni] = zv;

    int sr = tid & 63;
    int sg = tid >> 6;
    for (int kt = 0; kt <= qt; ++kt) {
        __syncthreads();
        long kvbase = ((long)(b * KSEL + kt * 64 + sr)) * 3072 + h * 64 + 1024;
        bf16x8 kv0 = *(const bf16x8*)(qkv + kvbase + sg * 16);
        bf16x8 kv1 = *(const bf16x8*)(qkv + kvbase + sg * 16 + 8);
        *(bf16x8*)(Ks + sr * APAD + sg * 16) = kv0;
        *(bf16x8*)(Ks + sr * APAD + sg * 16 + 8) = kv1;
        bf16x8 vv0 = *(const bf16x8*)(qkv + kvbase + 1024 + sg * 16);
        bf16x8 vv1 = *(const bf16x8*)(qkv + kvbase + 1024 + sg * 16 + 8);
#pragma unroll
        for (int i = 0; i < 8; ++i) {
            Vt[(sg * 16 + i) * APAD + sr] = vv0[i];
            Vt[(sg * 16 + 8 + i) * APAD + sr] = vv1[i];
        }
        __syncthreads();

        f32x4 S[4];
#pragma unroll
        for (int ni = 0; ni < 4; ++ni) S[ni] = zv;
#pragma unroll
        for (int ni = 0; ni < 4; ++ni) {
            bf16x8 kf0 = *(const bf16x8*)(Ks + (ni * 16 + l15) * APAD + l4 * 8);
            bf16x8 kf1 = *(const bf16x8*)(Ks + (ni * 16 + l15) * APAD + l4 * 8 + 32);
            S[ni] = __builtin_amdgcn_mfma_f32_16x16x32_bf16(qf[0], kf0, S[ni], 0, 0, 0);
            S[ni] = __builtin_amdgcn_mfma_f32_16x16x32_bf16(qf[1], kf1, S[ni], 0, 0, 0);
        }
        int rowb = qt * 64 + w * 16 + l4 * 4;
#pragma unroll
        for (int r = 0; r < 4; ++r) {
            float sv[4];
            float mx = -1e30f;
#pragma unroll
            for (int ni = 0; ni < 4; ++ni) {
                float x = S[ni][r] * 0.125f;
                int col = kt * 64 + ni * 16 + l15;
                if (col > rowb + r) x = -1e30f;
                sv[ni] = x;
                mx = fmaxf(mx, x);
            }
            mx = fmaxf(mx, __shfl_xor(mx, 1, 64));
            mx = fmaxf(mx, __shfl_xor(mx, 2, 64));
            mx = fmaxf(mx, __shfl_xor(mx, 4, 64));
            mx = fmaxf(mx, __shfl_xor(mx, 8, 64));
            float m_new = fmaxf(m_run[r], mx);
            float alpha = expf(m_run[r] - m_new);
            float ps = 0.f;
#pragma unroll
            for (int ni = 0; ni < 4; ++ni) {
                float e = expf(sv[ni] - m_new);
                sv[ni] = e;
                ps += e;
            }
            ps += __shfl_xor(ps, 1, 64);
            ps += __shfl_xor(ps, 2, 64);
            ps += __shfl_xor(ps, 4, 64);
            ps += __shfl_xor(ps, 8, 64);
            l_run[r] = l_run[r] * alpha + ps;
            m_run[r] = m_new;
#pragma unroll
            for (int ni = 0; ni < 4; ++ni) {
                O[ni][r] *= alpha;
                Ps[w][(l4 * 4 + r) * APAD + ni * 16 + l15] = (__bf16)sv[ni];
            }
        }
#pragma unroll
        for (int ks = 0; ks < 2; ++ks) {
            bf16x8 pf = *(const bf16x8*)(Ps[w] + l15 * APAD + ks * 32 + l4 * 8);
#pragma unroll
            for (int ni = 0; ni < 4; ++ni) {
                bf16x8 vf = *(const bf16x8*)(Vt + (ni * 16 + l15) * APAD + ks * 32 + l4 * 8);
                O[ni] = __builtin_amdgcn_mfma_f32_16x16x32_bf16(pf, vf, O[ni], 0, 0, 0);
            }
        }
    }
    long orow = (long)(b * KSEL + qt * 64 + w * 16);
#pragma unroll
    for (int r = 0; r < 4; ++r) {
        float inv = 1.0f / l_run[r];
#pragma unroll
        for (int ni = 0; ni < 4; ++ni)
            o[(orow + l4 * 4 + r) * DD + h * 64 + ni * 16 + l15] = (__bf16)(O[ni][r] * inv);
    }
}

// ---------------- BCE losses ----------------
__global__ __launch_bounds__(256) void bce_kernel(const float* __restrict__ scores,
                                                  const float* __restrict__ logits,
                                                  const float* __restrict__ flags,
                                                  const float* __restrict__ fc2b,
                                                  float* __restrict__ acc) {
    int i = blockIdx.x * 256 + threadIdx.x;
    int tid = threadIdx.x;
    __shared__ float r0[256];
    __shared__ float r1[256];
    float tgt = flags[i];
    r0[tid] = bce_term(scores[i], tgt);
    r1[tid] = bce_term(logits[i] + fc2b[0], tgt);
    __syncthreads();
    for (int s2 = 128; s2 > 0; s2 >>= 1) {
        if (tid < s2) { r0[tid] += r0[tid + s2]; r1[tid] += r1[tid + s2]; }
        __syncthreads();
    }
    if (tid == 0) {
        atomicAdd(acc + 0, r0[0]);
        atomicAdd(acc + 1, r1[0]);
    }
}

__global__ void finalize_kernel(const float* __restrict__ acc, float* __restrict__ out) {
    out[0] = (acc[0] / (float)BT) * 0.01f + (acc[1] / (float)BT) * 0.01f;
}

extern "C" void kernel_launch(void* const* d_in, const int* in_sizes, int n_in,
                              void* d_out, int out_size, void* d_ws, size_t ws_size,
                              hipStream_t stream) {
    const float* hidden = (const float*)d_in[0];
    const float* router_w = (const float*)d_in[1];
    const float* fc1_w = (const float*)d_in[2];
    const float* fc1_b = (const float*)d_in[3];
    const float* fc2_w = (const float*)d_in[4];
    const float* fc2_b = (const float*)d_in[5];
    const float* ln1_g = (const float*)d_in[6];
    const float* ln2_g = (const float*)d_in[7];
    const float* wq = (const float*)d_in[8];
    const float* wk = (const float*)d_in[9];
    const float* wv = (const float*)d_in[10];
    const float* wo = (const float*)d_in[11];
    const float* w_gate = (const float*)d_in[12];
    const float* w_up = (const float*)d_in[13];
    const float* w_down = (const float*)d_in[14];

    float* out = (float*)d_out;
    char* wsb = (char*)d_ws;

    // ---- workspace layout (peak 52.75 MiB; 54.75 MiB proven in R3) ----
    float* scores = (float*)(wsb);                 // 64K
    float* flags  = (float*)(wsb + 0x10000);       // 64K
    float* logits = (float*)(wsb + 0x20000);       // 64K
    int*   idx    = (int*)  (wsb + 0x30000);       // 8K
    float* gate   = (float*)(wsb + 0x32000);       // 8K
    float* acc    = (float*)(wsb + 0x34000);
    __bf16* fc1_t  = (__bf16*)(wsb + 0x40000);     // [256][1024]  512K
    __bf16* wo_t   = (__bf16*)(wsb + 0xC0000);     // [1024][1024] 2M
    __bf16* wqkv_t = (__bf16*)(wsb + 0x2C0000);    // [3072][1024] 6M -> 0x8C0000
    __bf16* hidden_bf = (__bf16*)(wsb + 0x8C0000);   // 32M -> 0x28C0000
    __bf16* qkv    = (__bf16*)(wsb + 0x8C0000);      // 12M (qkv GEMM -> attn)
    __bf16* a_bf   = (__bf16*)(wsb + 0x14C0000);     // 4M  (rms1 -> qkv GEMM)
    __bf16* act_bf = (__bf16*)(wsb + 0x8C0000);      // 16M (gateup -> down)
    __bf16* att_bf = (__bf16*)(wsb + 0x18C0000);     // 4M  (attn -> wo)
    __bf16* h_bf   = (__bf16*)(wsb + 0x1CC0000);     // 4M  (wo -> scatter)
    __bf16* m_bf   = (__bf16*)(wsb + 0x20C0000);     // 4M  (rms2 -> gateup)
    __bf16* wgu_t  = (__bf16*)(wsb + 0x24C0000);     // 16M (cast -> gateup) -> 0x34C0000
    __bf16* wd_t   = (__bf16*)(wsb + 0x24C0000);     // 8M  (cast after gateup -> down)
    __bf16* p0     = (__bf16*)(wsb + 0x2CC0000);     // 4M  (down -> scatter)
    __bf16* p1     = (__bf16*)(wsb + 0x30C0000);     // 4M  -> 0x34C0000

    // 1. zero accumulators
    hipMemsetAsync(acc, 0, 2 * sizeof(float), stream);
    hipMemsetAsync(logits, 0, BT * sizeof(float), stream);

    // 2. early weight casts (fc1, wq, wk, wv, wo) in one kernel
    {
        CPack p;
        p.nd = 5;
        p.d[0] = {fc1_w, fc1_t, DD, 256, 0, 0};
        p.d[1] = {wq, wqkv_t, DD, DD, 256, 0};
        p.d[2] = {wk, wqkv_t + (size_t)1024 * 1024, DD, DD, 1280, 0};
        p.d[3] = {wv, wqkv_t + (size_t)2048 * 1024, DD, DD, 2304, 0};
        p.d[4] = {wo, wo_t, DD, DD, 3328, 0};
        cast_multi<<<4352, 256, 0, stream>>>(p);
    }

    // 3. fused passthrough copy + bf16 cast + router scores; radix top-k
    fused_pass<<<BT / 4, 256, 0, stream>>>(hidden, router_w, out, hidden_bf, scores);
    topk_radix<<<BB, 1024, 0, stream>>>(scores, flags, idx, gate);

    // 4. predictor GEMM + BCE
    mfma_gemm<3><<<dim3(2, BT / 128), 256, 0, stream>>>(
        hidden_bf, fc1_t, BT, 256, DD, nullptr, nullptr, nullptr,
        fc1_b, fc2_w, logits);
    bce_kernel<<<BT / 256, 256, 0, stream>>>(scores, logits, flags, fc2_b, acc);

    // 5. gather + rmsnorm1 -> a_bf
    rms_kernel<float><<<MTOK, 256, 0, stream>>>(hidden, idx, ln1_g, a_bf);

    // 6. fused qkv projection (plain EP=0) + separate RoPE
    mfma_gemm<0><<<dim3(3072 / 128, MTOK / 128), 256, 0, stream>>>(
        a_bf, wqkv_t, MTOK, 3072, DD, qkv, nullptr, nullptr,
        nullptr, nullptr, nullptr);
    rope_kernel<<<MTOK, 512, 0, stream>>>(qkv, idx);

    // 7. MFMA flash attention
    attn_mfma<<<dim3(KSEL / 64, BB * NHH), 256, 0, stream>>>(qkv, att_bf);

    // 8. cast wg/wu interleaved -> wgu_t
    {
        CPack p;
        p.nd = 2;
        p.d[0] = {w_gate, wgu_t, DD, FF, 0, 1};
        p.d[1] = {w_up,   wgu_t, DD, FF, 4096, 2};
        cast_multi<<<8192, 256, 0, stream>>>(p);
    }

    // 9. Wo + residual -> h_bf
    mfma_gemm<1><<<dim3(DD / 128, MTOK / 128), 256, 0, stream>>>(
        att_bf, wo_t, MTOK, DD, DD, h_bf, hidden, idx,
        nullptr, nullptr, nullptr);

    // 10. rmsnorm2 -> m_bf
    rms_kernel<__bf16><<<MTOK, 256, 0, stream>>>(h_bf, nullptr, ln2_g, m_bf);

    // 11. 2-stream SwiGLU gate/up (interleaved N=8192) -> act_bf [2048][4096]
    gateup2_mfma<<<dim3(8192 / 128, MTOK / 128), 256, 0, stream>>>(m_bf, wgu_t, act_bf);

    // 12. cast w_down -> wd_t (wgu dead)
    {
        CPack p;
        p.nd = 1;
        p.d[0] = {w_down, wd_t, FF, DD, 0, 0};
        cast_multi<<<4096, 256, 0, stream>>>(p);
    }

    // 13. down proj split-K=2 -> bf16 partials
    down_gemm<<<dim3(DD / 128, MTOK / 128, 2), 256, 0, stream>>>(act_bf, wd_t, p0, p1);

    // 14. combine partials + gated scatter into out
    scatter_kernel<<<MTOK, 256, 0, stream>>>(p0, p1, h_bf, hidden, idx, gate, out);

    // 15. aux scalar
    finalize_kernel<<<1, 1, 0, stream>>>(acc, out + (size_t)BT * DD);
}